// Round 3
// baseline (5732.872 us; speedup 1.0000x reference)
//
#include <hip/hip_runtime.h>
#include <hip/hip_bf16.h>

// GATv2 x2 layers, N=100K, E=1.6M (+self loops), H=4, C=16, D=64, F_IN=128, f32.
// Pipeline: deg hist + scan -> 3-pass line-dense CSR sort (13 buckets -> 196
// windows -> per-window LDS-cursor scatter) -> [tiled gemm -> fused GAT] x 2.

typedef unsigned long long u64;

__device__ __forceinline__ float head_sum16(float v) {
    v += __shfl_xor(v, 1, 64);
    v += __shfl_xor(v, 2, 64);
    v += __shfl_xor(v, 4, 64);
    v += __shfl_xor(v, 8, 64);
    return v;
}

__global__ void hist_kernel(const int* __restrict__ dst, int* __restrict__ deg, int E) {
    int i = blockIdx.x * blockDim.x + threadIdx.x;
    int stride = gridDim.x * blockDim.x;
    for (; i < E; i += stride) atomicAdd(&deg[dst[i]], 1);
}

__global__ void scan_a(const int* __restrict__ deg, int* __restrict__ incl,
                       int* __restrict__ partials, int n) {
    __shared__ int sm[2][1024];
    int tid = threadIdx.x;
    int i = blockIdx.x * 1024 + tid;
    int v = (i < n) ? deg[i] : 0;
    sm[0][tid] = v;
    __syncthreads();
    int pin = 0;
    #pragma unroll
    for (int ofs = 1; ofs < 1024; ofs <<= 1) {
        int pout = pin ^ 1;
        sm[pout][tid] = sm[pin][tid] + ((tid >= ofs) ? sm[pin][tid - ofs] : 0);
        pin = pout;
        __syncthreads();
    }
    int r = sm[pin][tid];
    if (i < n) incl[i] = r;
    if (tid == 1023) partials[blockIdx.x] = r;
}

__global__ void scan_b(int* partials, int nblk) {
    __shared__ int sm[2][1024];
    int tid = threadIdx.x;
    int v = (tid < nblk) ? partials[tid] : 0;
    sm[0][tid] = v;
    __syncthreads();
    int pin = 0;
    #pragma unroll
    for (int ofs = 1; ofs < 1024; ofs <<= 1) {
        int pout = pin ^ 1;
        sm[pout][tid] = sm[pin][tid] + ((tid >= ofs) ? sm[pin][tid - ofs] : 0);
        pin = pout;
        __syncthreads();
    }
    if (tid < nblk) partials[tid] = sm[pin][tid] - v;  // exclusive
}

__global__ void scan_c(const int* __restrict__ deg, const int* __restrict__ incl,
                       const int* __restrict__ partials, int* __restrict__ offs,
                       int n, int E) {
    int i = blockIdx.x * blockDim.x + threadIdx.x;
    if (i < n) offs[i] = partials[i >> 10] + incl[i] - deg[i];
    if (i == 0) offs[n] = E;
}

__global__ void init_cursors(const int* __restrict__ offs, int* __restrict__ bcurA,
                             int* __restrict__ bcurB, int N) {
    int t = threadIdx.x;
    int nA = (N + 8191) >> 13;
    int nW = (N + 511) >> 9;
    if (t < nA) bcurA[t] = offs[min(t << 13, N)];
    if (t < nW) bcurB[t] = offs[min(t << 9, N)];
}

// pass A: edges -> 13 coarse buckets (dst>>13), wave-aggregated appends
__global__ void partA(const int* __restrict__ esrc, const int* __restrict__ edst,
                      u64* __restrict__ pairs, int* __restrict__ bcur, int E) {
    int lane = threadIdx.x & 63;
    int i = blockIdx.x * blockDim.x + threadIdx.x;
    int stride = gridDim.x * blockDim.x;
    for (; i < E; i += stride) {
        int s = esrc[i];
        int d = edst[i];
        int b = d >> 13;
        u64 todo = __ballot(1);
        while (todo) {
            int leader = __ffsll((unsigned long long)todo) - 1;
            int lb = __shfl(b, leader);
            u64 grp = __ballot(b == lb) & todo;
            int cnt = __popcll(grp);
            int base = 0;
            if (lane == leader) base = atomicAdd(&bcur[lb], cnt);
            base = __shfl(base, leader);
            if ((grp >> lane) & 1ull) {
                int rank = __popcll(grp & ((lane == 63) ? ~0ull >> 1 : ((1ull << lane) - 1ull)) & ((1ull << lane) - 1ull));
                pairs[base + rank] = ((u64)(unsigned)d << 32) | (unsigned)s;
            }
            todo ^= grp;
        }
    }
}

// pass B: bucket pairs -> 512-dst windows (dst>>9)
__global__ void partB(const u64* __restrict__ in, u64* __restrict__ out,
                      int* __restrict__ wcur, int E) {
    int lane = threadIdx.x & 63;
    int i = blockIdx.x * blockDim.x + threadIdx.x;
    int stride = gridDim.x * blockDim.x;
    for (; i < E; i += stride) {
        u64 pr = in[i];
        int d = (int)(pr >> 32);
        int w = d >> 9;
        u64 todo = __ballot(1);
        while (todo) {
            int leader = __ffsll((unsigned long long)todo) - 1;
            int lw = __shfl(w, leader);
            u64 grp = __ballot(w == lw) & todo;
            int cnt = __popcll(grp);
            int base = 0;
            if (lane == leader) base = atomicAdd(&wcur[lw], cnt);
            base = __shfl(base, leader);
            if ((grp >> lane) & 1ull) {
                int rank = __popcll(grp & ((1ull << lane) - 1ull));
                out[base + rank] = pr;
            }
            todo ^= grp;
        }
    }
}

// final: one block per window; LDS cursors; writes confined to ~32KB region
__global__ __launch_bounds__(256) void window_scatter(const u64* __restrict__ pairs,
                                                      const int* __restrict__ offs,
                                                      int* __restrict__ srcs, int N) {
    __shared__ int cur[512];
    int w = blockIdx.x;
    int d0 = w << 9;
    int nd = min(512, N - d0);
    for (int i = threadIdx.x; i < nd; i += 256) cur[i] = offs[d0 + i];
    __syncthreads();
    int p0 = offs[d0];
    int p1 = offs[min(d0 + 512, N)];
    for (int idx = p0 + threadIdx.x; idx < p1; idx += 256) {
        u64 pr = pairs[idx];
        int d = (int)(pr >> 32);
        int s = (int)(pr & 0xffffffffu);
        int pos = atomicAdd(&cur[d - d0], 1);
        srcs[pos] = s;
    }
}

// Tiled GEMM: [xl | xr] = X @ [Wl | Wr].  X: [N,K], Wl/Wr: [K,64].
// 64 rows x 128 cols per block, 256 threads, 4x8 micro-tile.
// W swizzle: insert 4-float gap per 32 cols -> <=2-way bank conflict (free).
#define WIDX(c) ((c) + (((c) >> 5) << 2))
template <int K>
__global__ __launch_bounds__(256) void gemm_lr(const float* __restrict__ X,
                                               const float* __restrict__ Wl,
                                               const float* __restrict__ Wr,
                                               float* __restrict__ xl,
                                               float* __restrict__ xr, int N) {
    constexpr int BM = 64;
    constexpr int LDW = 140;
    constexpr int LDX = K + 4;
    __shared__ float Ws[K][LDW];
    __shared__ float Xs[BM][LDX];
    const int tid = threadIdx.x;
    const int rbase = blockIdx.x * BM;

    for (int f = tid; f < K * 16; f += 256) {
        int k = f >> 4;
        int c = (f & 15) << 2;
        float4 a = *reinterpret_cast<const float4*>(&Wl[k * 64 + c]);
        float4 b = *reinterpret_cast<const float4*>(&Wr[k * 64 + c]);
        *reinterpret_cast<float4*>(&Ws[k][WIDX(c)]) = a;
        *reinterpret_cast<float4*>(&Ws[k][WIDX(64 + c)]) = b;
    }
    for (int f = tid; f < BM * (K / 4); f += 256) {
        int m = f / (K / 4);
        int k4 = f % (K / 4);
        int r = rbase + m;
        float4 v = (r < N) ? *reinterpret_cast<const float4*>(&X[(size_t)r * K + k4 * 4])
                           : make_float4(0.f, 0.f, 0.f, 0.f);
        *reinterpret_cast<float4*>(&Xs[m][k4 * 4]) = v;
    }
    __syncthreads();

    const int tx = tid & 15;
    const int ty = tid >> 4;
    const int c0 = tx * 8;
    const int r0 = ty * 4;
    const int wc = WIDX(c0);

    float acc[4][8];
    #pragma unroll
    for (int j = 0; j < 4; ++j)
        #pragma unroll
        for (int i = 0; i < 8; ++i) acc[j][i] = 0.f;

    #pragma unroll 2
    for (int k4 = 0; k4 < K; k4 += 4) {
        float4 xv[4];
        #pragma unroll
        for (int j = 0; j < 4; ++j)
            xv[j] = *reinterpret_cast<const float4*>(&Xs[r0 + j][k4]);
        #pragma unroll
        for (int kk = 0; kk < 4; ++kk) {
            float4 w0 = *reinterpret_cast<const float4*>(&Ws[k4 + kk][wc]);
            float4 w1 = *reinterpret_cast<const float4*>(&Ws[k4 + kk][wc + 4]);
            float w[8] = {w0.x, w0.y, w0.z, w0.w, w1.x, w1.y, w1.z, w1.w};
            #pragma unroll
            for (int j = 0; j < 4; ++j) {
                float xk = (kk == 0) ? xv[j].x : (kk == 1) ? xv[j].y : (kk == 2) ? xv[j].z : xv[j].w;
                #pragma unroll
                for (int i = 0; i < 8; ++i)
                    acc[j][i] = fmaf(xk, w[i], acc[j][i]);
            }
        }
    }

    float* op = (c0 < 64) ? xl : xr;
    const int cc = c0 & 63;
    #pragma unroll
    for (int j = 0; j < 4; ++j) {
        int r = rbase + r0 + j;
        if (r < N) {
            float4 v0 = make_float4(acc[j][0], acc[j][1], acc[j][2], acc[j][3]);
            float4 v1 = make_float4(acc[j][4], acc[j][5], acc[j][6], acc[j][7]);
            *reinterpret_cast<float4*>(&op[(size_t)r * 64 + cc]) = v0;
            *reinterpret_cast<float4*>(&op[(size_t)r * 64 + cc + 4]) = v1;
        }
    }
}

// one wave per destination node; unnormalized softmax (logits bounded in f32);
// unroll-4 to keep 4 gathers in flight.
__global__ __launch_bounds__(256) void gat_kernel(const float* __restrict__ xl,
                                                  const float* __restrict__ xr,
                                                  const int* __restrict__ offs,
                                                  const int* __restrict__ srcs,
                                                  const float* __restrict__ att,
                                                  const float* __restrict__ bias,
                                                  float* __restrict__ out, int N) {
    int lane = threadIdx.x & 63;
    int wid = threadIdx.x >> 6;
    int n = blockIdx.x * 4 + wid;
    if (n >= N) return;
    float att_l = att[lane];
    float b_l = bias[lane];
    float xr_d = xr[(size_t)n * 64 + lane];
    float xls = xl[(size_t)n * 64 + lane];
    float v = xls + xr_d;
    float p = __expf(head_sum16(att_l * fmaxf(v, 0.2f * v)));
    float s0 = p, s1 = 0.f, s2 = 0.f, s3 = 0.f;
    float o0 = xls * p, o1 = 0.f, o2 = 0.f, o3 = 0.f;
    int e0 = offs[n], e1 = offs[n + 1];
    int j = e0;
    for (; j + 3 < e1; j += 4) {
        int sa = srcs[j], sb = srcs[j + 1], sc = srcs[j + 2], sd = srcs[j + 3];
        float xa = xl[(size_t)sa * 64 + lane];
        float xb = xl[(size_t)sb * 64 + lane];
        float xc = xl[(size_t)sc * 64 + lane];
        float xd = xl[(size_t)sd * 64 + lane];
        float ua = xa + xr_d, ub = xb + xr_d, uc = xc + xr_d, ud = xd + xr_d;
        float pa = __expf(head_sum16(att_l * fmaxf(ua, 0.2f * ua)));
        float pb = __expf(head_sum16(att_l * fmaxf(ub, 0.2f * ub)));
        float pc = __expf(head_sum16(att_l * fmaxf(uc, 0.2f * uc)));
        float pd = __expf(head_sum16(att_l * fmaxf(ud, 0.2f * ud)));
        s0 += pa; s1 += pb; s2 += pc; s3 += pd;
        o0 = fmaf(xa, pa, o0);
        o1 = fmaf(xb, pb, o1);
        o2 = fmaf(xc, pc, o2);
        o3 = fmaf(xd, pd, o3);
    }
    for (; j < e1; ++j) {
        int sa = srcs[j];
        float xa = xl[(size_t)sa * 64 + lane];
        float ua = xa + xr_d;
        float pa = __expf(head_sum16(att_l * fmaxf(ua, 0.2f * ua)));
        s1 += pa;
        o1 = fmaf(xa, pa, o1);
    }
    float s = (s0 + s1) + (s2 + s3);
    float o = (o0 + o1) + (o2 + o3);
    out[(size_t)n * 64 + lane] = fmaxf(o / s + b_l, 0.f);
}

extern "C" void kernel_launch(void* const* d_in, const int* in_sizes, int n_in,
                              void* d_out, int out_size, void* d_ws, size_t ws_size,
                              hipStream_t stream) {
    const float* x    = (const float*)d_in[0];
    const int*   edge = (const int*)d_in[1];
    const float* W1l  = (const float*)d_in[2];
    const float* W1r  = (const float*)d_in[3];
    const float* att1 = (const float*)d_in[4];
    const float* b1   = (const float*)d_in[5];
    const float* W2l  = (const float*)d_in[6];
    const float* W2r  = (const float*)d_in[7];
    const float* att2 = (const float*)d_in[8];
    const float* b2   = (const float*)d_in[9];

    const int N = in_sizes[0] / 128;  // 100000
    const int E = in_sizes[1] / 2;    // 1600000
    const int* esrc = edge;
    const int* edst = edge + E;

    char* ws = (char*)d_ws;
    size_t off = 0;
    auto alloc = [&](size_t bytes) {
        void* p = ws + off;
        off += (bytes + 255) & ~(size_t)255;
        return p;
    };
    float* xl     = (float*)alloc((size_t)N * 64 * 4);
    float* xr     = (float*)alloc((size_t)N * 64 * 4);
    float* h      = (float*)alloc((size_t)N * 64 * 4);
    int* deg      = (int*)alloc((size_t)N * 4);
    int* incl     = (int*)alloc((size_t)N * 4);
    int* offs     = (int*)alloc((size_t)(N + 1) * 4);
    int* partials = (int*)alloc(1024 * 4);
    int* srcs     = (int*)alloc((size_t)E * 4);
    u64* pairsA   = (u64*)alloc((size_t)E * 8);
    u64* pairsB   = (u64*)alloc((size_t)E * 8);
    int* bcurA    = (int*)alloc(64 * 4);
    int* bcurB    = (int*)alloc(256 * 4);
    (void)ws_size;

    hipMemsetAsync(deg, 0, (size_t)N * 4, stream);

    const int nblk = (N + 1023) >> 10;
    const int nW = (N + 511) >> 9;
    hist_kernel<<<1024, 256, 0, stream>>>(edst, deg, E);
    scan_a<<<nblk, 1024, 0, stream>>>(deg, incl, partials, N);
    scan_b<<<1, 1024, 0, stream>>>(partials, nblk);
    scan_c<<<(N + 255) / 256, 256, 0, stream>>>(deg, incl, partials, offs, N, E);
    init_cursors<<<1, 256, 0, stream>>>(offs, bcurA, bcurB, N);
    partA<<<1024, 256, 0, stream>>>(esrc, edst, pairsA, bcurA, E);
    partB<<<1024, 256, 0, stream>>>(pairsA, pairsB, bcurB, E);
    window_scatter<<<nW, 256, 0, stream>>>(pairsB, offs, srcs, N);

    const int gblk = (N + 63) / 64;
    gemm_lr<128><<<gblk, 256, 0, stream>>>(x, W1l, W1r, xl, xr, N);
    gat_kernel<<<(N + 3) / 4, 256, 0, stream>>>(xl, xr, offs, srcs, att1, b1, h, N);
    gemm_lr<64><<<gblk, 256, 0, stream>>>(h, W2l, W2r, xl, xr, N);
    gat_kernel<<<(N + 3) / 4, 256, 0, stream>>>(xl, xr, offs, srcs, att2, b2, (float*)d_out, N);
}

// Round 4
// 505.080 us; speedup vs baseline: 11.3504x; 11.3504x over previous
//
#include <hip/hip_runtime.h>
#include <hip/hip_bf16.h>

// GATv2 x2 layers, N=100K, E=1.6M (+self loops), H=4, C=16, D=64, F_IN=128, f32.
// CSR build: deg hist + scan -> deterministic radix partition into 512-dst
// windows (block-chunk LDS hist -> per-window scan -> place, NO global atomics)
// -> per-window LDS-cursor scatter. Then [tiled gemm -> fused GAT] x 2.

typedef unsigned long long u64;

#define NBLK_S 512  // edge-chunk blocks for the partition passes

__device__ __forceinline__ float head_sum16(float v) {
    v += __shfl_xor(v, 1, 64);
    v += __shfl_xor(v, 2, 64);
    v += __shfl_xor(v, 4, 64);
    v += __shfl_xor(v, 8, 64);
    return v;
}

__global__ void hist_kernel(const int* __restrict__ dst, int* __restrict__ deg, int E) {
    int i = blockIdx.x * blockDim.x + threadIdx.x;
    int stride = gridDim.x * blockDim.x;
    for (; i < E; i += stride) atomicAdd(&deg[dst[i]], 1);
}

__global__ void scan_a(const int* __restrict__ deg, int* __restrict__ incl,
                       int* __restrict__ partials, int n) {
    __shared__ int sm[2][1024];
    int tid = threadIdx.x;
    int i = blockIdx.x * 1024 + tid;
    int v = (i < n) ? deg[i] : 0;
    sm[0][tid] = v;
    __syncthreads();
    int pin = 0;
    #pragma unroll
    for (int ofs = 1; ofs < 1024; ofs <<= 1) {
        int pout = pin ^ 1;
        sm[pout][tid] = sm[pin][tid] + ((tid >= ofs) ? sm[pin][tid - ofs] : 0);
        pin = pout;
        __syncthreads();
    }
    int r = sm[pin][tid];
    if (i < n) incl[i] = r;
    if (tid == 1023) partials[blockIdx.x] = r;
}

__global__ void scan_b(int* partials, int nblk) {
    __shared__ int sm[2][1024];
    int tid = threadIdx.x;
    int v = (tid < nblk) ? partials[tid] : 0;
    sm[0][tid] = v;
    __syncthreads();
    int pin = 0;
    #pragma unroll
    for (int ofs = 1; ofs < 1024; ofs <<= 1) {
        int pout = pin ^ 1;
        sm[pout][tid] = sm[pin][tid] + ((tid >= ofs) ? sm[pin][tid - ofs] : 0);
        pin = pout;
        __syncthreads();
    }
    if (tid < nblk) partials[tid] = sm[pin][tid] - v;  // exclusive
}

__global__ void scan_c(const int* __restrict__ deg, const int* __restrict__ incl,
                       const int* __restrict__ partials, int* __restrict__ offs,
                       int n, int E) {
    int i = blockIdx.x * blockDim.x + threadIdx.x;
    if (i < n) offs[i] = partials[i >> 10] + incl[i] - deg[i];
    if (i == 0) offs[n] = E;
}

// s1: per-block LDS histogram of 512-dst windows over this block's edge chunk
__global__ __launch_bounds__(256) void sort_hist(const int* __restrict__ edst,
                                                 int* __restrict__ gh, int E, int nW) {
    __shared__ int h[256];
    for (int i = threadIdx.x; i < nW; i += 256) h[i] = 0;
    __syncthreads();
    const int chunk = (E + NBLK_S - 1) / NBLK_S;
    const int lo = blockIdx.x * chunk;
    const int hi = min(E, lo + chunk);
    for (int i = lo + threadIdx.x; i < hi; i += 256)
        atomicAdd(&h[edst[i] >> 9], 1);
    __syncthreads();
    for (int w = threadIdx.x; w < nW; w += 256)
        gh[w * NBLK_S + blockIdx.x] = h[w];
}

// s2: per-window exclusive scan over the 512 block counts (+ window base)
__global__ __launch_bounds__(NBLK_S) void sort_scan(const int* __restrict__ offs,
                                                    int* __restrict__ gh, int N) {
    __shared__ int sm[2][NBLK_S];
    const int w = blockIdx.x;
    const int t = threadIdx.x;
    int v = gh[w * NBLK_S + t];
    sm[0][t] = v;
    __syncthreads();
    int pin = 0;
    #pragma unroll
    for (int ofs = 1; ofs < NBLK_S; ofs <<= 1) {
        int pout = pin ^ 1;
        sm[pout][t] = sm[pin][t] + ((t >= ofs) ? sm[pin][t - ofs] : 0);
        pin = pout;
        __syncthreads();
    }
    gh[w * NBLK_S + t] = offs[w << 9] + sm[pin][t] - v;  // exclusive + base
}

// s3: re-read chunk, place (dst,src) pairs via LDS cursors (no global atomics)
__global__ __launch_bounds__(256) void sort_place(const int* __restrict__ esrc,
                                                  const int* __restrict__ edst,
                                                  const int* __restrict__ gh,
                                                  u64* __restrict__ pairs, int E, int nW) {
    __shared__ int cur[256];
    for (int i = threadIdx.x; i < nW; i += 256)
        cur[i] = gh[i * NBLK_S + blockIdx.x];
    __syncthreads();
    const int chunk = (E + NBLK_S - 1) / NBLK_S;
    const int lo = blockIdx.x * chunk;
    const int hi = min(E, lo + chunk);
    for (int i = lo + threadIdx.x; i < hi; i += 256) {
        int d = edst[i];
        int s = esrc[i];
        int pos = atomicAdd(&cur[d >> 9], 1);
        pairs[pos] = ((u64)(unsigned)d << 32) | (unsigned)s;
    }
}

// s4: one block per window; LDS cursors; writes confined to ~32KB region
__global__ __launch_bounds__(256) void window_scatter(const u64* __restrict__ pairs,
                                                      const int* __restrict__ offs,
                                                      int* __restrict__ srcs, int N) {
    __shared__ int cur[512];
    int w = blockIdx.x;
    int d0 = w << 9;
    int nd = min(512, N - d0);
    for (int i = threadIdx.x; i < nd; i += 256) cur[i] = offs[d0 + i];
    __syncthreads();
    int p0 = offs[d0];
    int p1 = offs[min(d0 + 512, N)];
    for (int idx = p0 + threadIdx.x; idx < p1; idx += 256) {
        u64 pr = pairs[idx];
        int d = (int)(pr >> 32);
        int s = (int)(pr & 0xffffffffu);
        int pos = atomicAdd(&cur[d - d0], 1);
        srcs[pos] = s;
    }
}

// Tiled GEMM: [xl | xr] = X @ [Wl | Wr].  X: [N,K], Wl/Wr: [K,64].
// 64 rows x 128 cols per block, 256 threads, 4x8 micro-tile.
#define WIDX(c) ((c) + (((c) >> 5) << 2))
template <int K>
__global__ __launch_bounds__(256) void gemm_lr(const float* __restrict__ X,
                                               const float* __restrict__ Wl,
                                               const float* __restrict__ Wr,
                                               float* __restrict__ xl,
                                               float* __restrict__ xr, int N) {
    constexpr int BM = 64;
    constexpr int LDW = 140;
    constexpr int LDX = K + 4;
    __shared__ float Ws[K][LDW];
    __shared__ float Xs[BM][LDX];
    const int tid = threadIdx.x;
    const int rbase = blockIdx.x * BM;

    for (int f = tid; f < K * 16; f += 256) {
        int k = f >> 4;
        int c = (f & 15) << 2;
        float4 a = *reinterpret_cast<const float4*>(&Wl[k * 64 + c]);
        float4 b = *reinterpret_cast<const float4*>(&Wr[k * 64 + c]);
        *reinterpret_cast<float4*>(&Ws[k][WIDX(c)]) = a;
        *reinterpret_cast<float4*>(&Ws[k][WIDX(64 + c)]) = b;
    }
    for (int f = tid; f < BM * (K / 4); f += 256) {
        int m = f / (K / 4);
        int k4 = f % (K / 4);
        int r = rbase + m;
        float4 v = (r < N) ? *reinterpret_cast<const float4*>(&X[(size_t)r * K + k4 * 4])
                           : make_float4(0.f, 0.f, 0.f, 0.f);
        *reinterpret_cast<float4*>(&Xs[m][k4 * 4]) = v;
    }
    __syncthreads();

    const int tx = tid & 15;
    const int ty = tid >> 4;
    const int c0 = tx * 8;
    const int r0 = ty * 4;
    const int wc = WIDX(c0);

    float acc[4][8];
    #pragma unroll
    for (int j = 0; j < 4; ++j)
        #pragma unroll
        for (int i = 0; i < 8; ++i) acc[j][i] = 0.f;

    #pragma unroll 2
    for (int k4 = 0; k4 < K; k4 += 4) {
        float4 xv[4];
        #pragma unroll
        for (int j = 0; j < 4; ++j)
            xv[j] = *reinterpret_cast<const float4*>(&Xs[r0 + j][k4]);
        #pragma unroll
        for (int kk = 0; kk < 4; ++kk) {
            float4 w0 = *reinterpret_cast<const float4*>(&Ws[k4 + kk][wc]);
            float4 w1 = *reinterpret_cast<const float4*>(&Ws[k4 + kk][wc + 4]);
            float w[8] = {w0.x, w0.y, w0.z, w0.w, w1.x, w1.y, w1.z, w1.w};
            #pragma unroll
            for (int j = 0; j < 4; ++j) {
                float xk = (kk == 0) ? xv[j].x : (kk == 1) ? xv[j].y : (kk == 2) ? xv[j].z : xv[j].w;
                #pragma unroll
                for (int i = 0; i < 8; ++i)
                    acc[j][i] = fmaf(xk, w[i], acc[j][i]);
            }
        }
    }

    float* op = (c0 < 64) ? xl : xr;
    const int cc = c0 & 63;
    #pragma unroll
    for (int j = 0; j < 4; ++j) {
        int r = rbase + r0 + j;
        if (r < N) {
            float4 v0 = make_float4(acc[j][0], acc[j][1], acc[j][2], acc[j][3]);
            float4 v1 = make_float4(acc[j][4], acc[j][5], acc[j][6], acc[j][7]);
            *reinterpret_cast<float4*>(&op[(size_t)r * 64 + cc]) = v0;
            *reinterpret_cast<float4*>(&op[(size_t)r * 64 + cc + 4]) = v1;
        }
    }
}

// one wave per destination node; unnormalized softmax (logits bounded in f32);
// unroll-4 to keep 4 gathers in flight.
__global__ __launch_bounds__(256) void gat_kernel(const float* __restrict__ xl,
                                                  const float* __restrict__ xr,
                                                  const int* __restrict__ offs,
                                                  const int* __restrict__ srcs,
                                                  const float* __restrict__ att,
                                                  const float* __restrict__ bias,
                                                  float* __restrict__ out, int N) {
    int lane = threadIdx.x & 63;
    int wid = threadIdx.x >> 6;
    int n = blockIdx.x * 4 + wid;
    if (n >= N) return;
    float att_l = att[lane];
    float b_l = bias[lane];
    float xr_d = xr[(size_t)n * 64 + lane];
    float xls = xl[(size_t)n * 64 + lane];
    float v = xls + xr_d;
    float p = __expf(head_sum16(att_l * fmaxf(v, 0.2f * v)));
    float s0 = p, s1 = 0.f, s2 = 0.f, s3 = 0.f;
    float o0 = xls * p, o1 = 0.f, o2 = 0.f, o3 = 0.f;
    int e0 = offs[n], e1 = offs[n + 1];
    int j = e0;
    for (; j + 3 < e1; j += 4) {
        int sa = srcs[j], sb = srcs[j + 1], sc = srcs[j + 2], sd = srcs[j + 3];
        float xa = xl[(size_t)sa * 64 + lane];
        float xb = xl[(size_t)sb * 64 + lane];
        float xc = xl[(size_t)sc * 64 + lane];
        float xd = xl[(size_t)sd * 64 + lane];
        float ua = xa + xr_d, ub = xb + xr_d, uc = xc + xr_d, ud = xd + xr_d;
        float pa = __expf(head_sum16(att_l * fmaxf(ua, 0.2f * ua)));
        float pb = __expf(head_sum16(att_l * fmaxf(ub, 0.2f * ub)));
        float pc = __expf(head_sum16(att_l * fmaxf(uc, 0.2f * uc)));
        float pd = __expf(head_sum16(att_l * fmaxf(ud, 0.2f * ud)));
        s0 += pa; s1 += pb; s2 += pc; s3 += pd;
        o0 = fmaf(xa, pa, o0);
        o1 = fmaf(xb, pb, o1);
        o2 = fmaf(xc, pc, o2);
        o3 = fmaf(xd, pd, o3);
    }
    for (; j < e1; ++j) {
        int sa = srcs[j];
        float xa = xl[(size_t)sa * 64 + lane];
        float ua = xa + xr_d;
        float pa = __expf(head_sum16(att_l * fmaxf(ua, 0.2f * ua)));
        s1 += pa;
        o1 = fmaf(xa, pa, o1);
    }
    float s = (s0 + s1) + (s2 + s3);
    float o = (o0 + o1) + (o2 + o3);
    out[(size_t)n * 64 + lane] = fmaxf(o / s + b_l, 0.f);
}

extern "C" void kernel_launch(void* const* d_in, const int* in_sizes, int n_in,
                              void* d_out, int out_size, void* d_ws, size_t ws_size,
                              hipStream_t stream) {
    const float* x    = (const float*)d_in[0];
    const int*   edge = (const int*)d_in[1];
    const float* W1l  = (const float*)d_in[2];
    const float* W1r  = (const float*)d_in[3];
    const float* att1 = (const float*)d_in[4];
    const float* b1   = (const float*)d_in[5];
    const float* W2l  = (const float*)d_in[6];
    const float* W2r  = (const float*)d_in[7];
    const float* att2 = (const float*)d_in[8];
    const float* b2   = (const float*)d_in[9];

    const int N = in_sizes[0] / 128;  // 100000
    const int E = in_sizes[1] / 2;    // 1600000
    const int* esrc = edge;
    const int* edst = edge + E;

    char* ws = (char*)d_ws;
    size_t off = 0;
    auto alloc = [&](size_t bytes) {
        void* p = ws + off;
        off += (bytes + 255) & ~(size_t)255;
        return p;
    };
    float* xl     = (float*)alloc((size_t)N * 64 * 4);
    float* xr     = (float*)alloc((size_t)N * 64 * 4);
    float* h      = (float*)alloc((size_t)N * 64 * 4);
    int* deg      = (int*)alloc((size_t)N * 4);
    int* incl     = (int*)alloc((size_t)N * 4);
    int* offs     = (int*)alloc((size_t)(N + 1) * 4);
    int* partials = (int*)alloc(1024 * 4);
    int* srcs     = (int*)alloc((size_t)E * 4);
    u64* pairs    = (u64*)alloc((size_t)E * 8);
    int* gh       = (int*)alloc((size_t)256 * NBLK_S * 4);
    (void)ws_size;

    hipMemsetAsync(deg, 0, (size_t)N * 4, stream);

    const int nblk = (N + 1023) >> 10;
    const int nW = (N + 511) >> 9;  // 196 windows
    hist_kernel<<<1024, 256, 0, stream>>>(edst, deg, E);
    scan_a<<<nblk, 1024, 0, stream>>>(deg, incl, partials, N);
    scan_b<<<1, 1024, 0, stream>>>(partials, nblk);
    scan_c<<<(N + 255) / 256, 256, 0, stream>>>(deg, incl, partials, offs, N, E);
    sort_hist<<<NBLK_S, 256, 0, stream>>>(edst, gh, E, nW);
    sort_scan<<<nW, NBLK_S, 0, stream>>>(offs, gh, N);
    sort_place<<<NBLK_S, 256, 0, stream>>>(esrc, edst, gh, pairs, E, nW);
    window_scatter<<<nW, 256, 0, stream>>>(pairs, offs, srcs, N);

    const int gblk = (N + 63) / 64;
    gemm_lr<128><<<gblk, 256, 0, stream>>>(x, W1l, W1r, xl, xr, N);
    gat_kernel<<<(N + 3) / 4, 256, 0, stream>>>(xl, xr, offs, srcs, att1, b1, h, N);
    gemm_lr<64><<<gblk, 256, 0, stream>>>(h, W2l, W2r, xl, xr, N);
    gat_kernel<<<(N + 3) / 4, 256, 0, stream>>>(xl, xr, offs, srcs, att2, b2, (float*)d_out, N);
}

// Round 5
// 472.008 us; speedup vs baseline: 12.1457x; 1.0701x over previous
//
#include <hip/hip_runtime.h>
#include <hip/hip_bf16.h>

// GATv2 x2 layers, N=100K, E=1.6M (+self loops), H=4, C=16, D=64, F_IN=128, f32.
// CSR build: deg hist + scan -> deterministic radix partition into 512-dst
// windows (block-chunk LDS hist -> per-window scan -> place, NO global atomics)
// -> per-window LDS-cursor scatter. Then [tiled gemm -> fused GAT] x 2.
// GEMM v3: K-tiled (KT=64, 53KB LDS -> 3 blocks/CU), row-remap (ty+16j) for
// conflict-free Xs reads, WIDX-swizzled Ws.

typedef unsigned long long u64;

#define NBLK_S 512  // edge-chunk blocks for the partition passes

__device__ __forceinline__ float head_sum16(float v) {
    v += __shfl_xor(v, 1, 64);
    v += __shfl_xor(v, 2, 64);
    v += __shfl_xor(v, 4, 64);
    v += __shfl_xor(v, 8, 64);
    return v;
}

__global__ void hist_kernel(const int* __restrict__ dst, int* __restrict__ deg, int E) {
    int i = blockIdx.x * blockDim.x + threadIdx.x;
    int stride = gridDim.x * blockDim.x;
    for (; i < E; i += stride) atomicAdd(&deg[dst[i]], 1);
}

__global__ void scan_a(const int* __restrict__ deg, int* __restrict__ incl,
                       int* __restrict__ partials, int n) {
    __shared__ int sm[2][1024];
    int tid = threadIdx.x;
    int i = blockIdx.x * 1024 + tid;
    int v = (i < n) ? deg[i] : 0;
    sm[0][tid] = v;
    __syncthreads();
    int pin = 0;
    #pragma unroll
    for (int ofs = 1; ofs < 1024; ofs <<= 1) {
        int pout = pin ^ 1;
        sm[pout][tid] = sm[pin][tid] + ((tid >= ofs) ? sm[pin][tid - ofs] : 0);
        pin = pout;
        __syncthreads();
    }
    int r = sm[pin][tid];
    if (i < n) incl[i] = r;
    if (tid == 1023) partials[blockIdx.x] = r;
}

__global__ void scan_b(int* partials, int nblk) {
    __shared__ int sm[2][1024];
    int tid = threadIdx.x;
    int v = (tid < nblk) ? partials[tid] : 0;
    sm[0][tid] = v;
    __syncthreads();
    int pin = 0;
    #pragma unroll
    for (int ofs = 1; ofs < 1024; ofs <<= 1) {
        int pout = pin ^ 1;
        sm[pout][tid] = sm[pin][tid] + ((tid >= ofs) ? sm[pin][tid - ofs] : 0);
        pin = pout;
        __syncthreads();
    }
    if (tid < nblk) partials[tid] = sm[pin][tid] - v;  // exclusive
}

__global__ void scan_c(const int* __restrict__ deg, const int* __restrict__ incl,
                       const int* __restrict__ partials, int* __restrict__ offs,
                       int n, int E) {
    int i = blockIdx.x * blockDim.x + threadIdx.x;
    if (i < n) offs[i] = partials[i >> 10] + incl[i] - deg[i];
    if (i == 0) offs[n] = E;
}

// s1: per-block LDS histogram of 512-dst windows over this block's edge chunk
__global__ __launch_bounds__(256) void sort_hist(const int* __restrict__ edst,
                                                 int* __restrict__ gh, int E, int nW) {
    __shared__ int h[256];
    for (int i = threadIdx.x; i < nW; i += 256) h[i] = 0;
    __syncthreads();
    const int chunk = (E + NBLK_S - 1) / NBLK_S;
    const int lo = blockIdx.x * chunk;
    const int hi = min(E, lo + chunk);
    for (int i = lo + threadIdx.x; i < hi; i += 256)
        atomicAdd(&h[edst[i] >> 9], 1);
    __syncthreads();
    for (int w = threadIdx.x; w < nW; w += 256)
        gh[w * NBLK_S + blockIdx.x] = h[w];
}

// s2: per-window exclusive scan over the 512 block counts (+ window base)
__global__ __launch_bounds__(NBLK_S) void sort_scan(const int* __restrict__ offs,
                                                    int* __restrict__ gh, int N) {
    __shared__ int sm[2][NBLK_S];
    const int w = blockIdx.x;
    const int t = threadIdx.x;
    int v = gh[w * NBLK_S + t];
    sm[0][t] = v;
    __syncthreads();
    int pin = 0;
    #pragma unroll
    for (int ofs = 1; ofs < NBLK_S; ofs <<= 1) {
        int pout = pin ^ 1;
        sm[pout][t] = sm[pin][t] + ((t >= ofs) ? sm[pin][t - ofs] : 0);
        pin = pout;
        __syncthreads();
    }
    gh[w * NBLK_S + t] = offs[w << 9] + sm[pin][t] - v;  // exclusive + base
}

// s3: re-read chunk, place (dst,src) pairs via LDS cursors (no global atomics)
__global__ __launch_bounds__(256) void sort_place(const int* __restrict__ esrc,
                                                  const int* __restrict__ edst,
                                                  const int* __restrict__ gh,
                                                  u64* __restrict__ pairs, int E, int nW) {
    __shared__ int cur[256];
    for (int i = threadIdx.x; i < nW; i += 256)
        cur[i] = gh[i * NBLK_S + blockIdx.x];
    __syncthreads();
    const int chunk = (E + NBLK_S - 1) / NBLK_S;
    const int lo = blockIdx.x * chunk;
    const int hi = min(E, lo + chunk);
    for (int i = lo + threadIdx.x; i < hi; i += 256) {
        int d = edst[i];
        int s = esrc[i];
        int pos = atomicAdd(&cur[d >> 9], 1);
        pairs[pos] = ((u64)(unsigned)d << 32) | (unsigned)s;
    }
}

// s4: one block per window; LDS cursors; writes confined to ~32KB region
__global__ __launch_bounds__(256) void window_scatter(const u64* __restrict__ pairs,
                                                      const int* __restrict__ offs,
                                                      int* __restrict__ srcs, int N) {
    __shared__ int cur[512];
    int w = blockIdx.x;
    int d0 = w << 9;
    int nd = min(512, N - d0);
    for (int i = threadIdx.x; i < nd; i += 256) cur[i] = offs[d0 + i];
    __syncthreads();
    int p0 = offs[d0];
    int p1 = offs[min(d0 + 512, N)];
    for (int idx = p0 + threadIdx.x; idx < p1; idx += 256) {
        u64 pr = pairs[idx];
        int d = (int)(pr >> 32);
        int s = (int)(pr & 0xffffffffu);
        int pos = atomicAdd(&cur[d - d0], 1);
        srcs[pos] = s;
    }
}

// Tiled GEMM: [xl | xr] = X @ [Wl | Wr].  X: [N,K], Wl/Wr: [K,64].
// Block: 64 rows x 128 cols, 256 threads. K-tiled KT=64 (53KB LDS, 3 blk/CU).
// Thread (tx,ty): cols 8*tx..+7 (WIDX-swizzled Ws, 2-way), rows ty+{0,16,32,48}
// (Xs bank offset (4*ty+k4)%32 -> 2-way = free).
#define WIDX(c) ((c) + (((c) >> 5) << 2))
template <int K>
__global__ __launch_bounds__(256) void gemm_lr(const float* __restrict__ X,
                                               const float* __restrict__ Wl,
                                               const float* __restrict__ Wr,
                                               float* __restrict__ xl,
                                               float* __restrict__ xr, int N) {
    constexpr int KT = 64;
    constexpr int LDW = 140;
    constexpr int LDX = KT + 4;  // 68
    __shared__ float Ws[KT][LDW];
    __shared__ float Xs[64][LDX];
    const int tid = threadIdx.x;
    const int rbase = blockIdx.x * 64;
    const int tx = tid & 15;
    const int ty = tid >> 4;
    const int c0 = tx * 8;
    const int wc = WIDX(c0);

    float acc[4][8];
    #pragma unroll
    for (int j = 0; j < 4; ++j)
        #pragma unroll
        for (int i = 0; i < 8; ++i) acc[j][i] = 0.f;

    #pragma unroll
    for (int t = 0; t < K / KT; ++t) {
        if (t) __syncthreads();  // protect LDS reuse across tiles
        for (int f = tid; f < KT * 16; f += 256) {
            int k = f >> 4;
            int c = (f & 15) << 2;
            float4 a = *reinterpret_cast<const float4*>(&Wl[(size_t)(t * KT + k) * 64 + c]);
            float4 b = *reinterpret_cast<const float4*>(&Wr[(size_t)(t * KT + k) * 64 + c]);
            *reinterpret_cast<float4*>(&Ws[k][WIDX(c)]) = a;
            *reinterpret_cast<float4*>(&Ws[k][WIDX(64 + c)]) = b;
        }
        for (int f = tid; f < 64 * (KT / 4); f += 256) {
            int m = f >> 4;
            int k4 = (f & 15) << 2;
            int r = rbase + m;
            float4 v = (r < N) ? *reinterpret_cast<const float4*>(&X[(size_t)r * K + t * KT + k4])
                               : make_float4(0.f, 0.f, 0.f, 0.f);
            *reinterpret_cast<float4*>(&Xs[m][k4]) = v;
        }
        __syncthreads();

        #pragma unroll 2
        for (int k4 = 0; k4 < KT; k4 += 4) {
            float4 xv[4];
            #pragma unroll
            for (int j = 0; j < 4; ++j)
                xv[j] = *reinterpret_cast<const float4*>(&Xs[ty + 16 * j][k4]);
            #pragma unroll
            for (int kk = 0; kk < 4; ++kk) {
                float4 w0 = *reinterpret_cast<const float4*>(&Ws[k4 + kk][wc]);
                float4 w1 = *reinterpret_cast<const float4*>(&Ws[k4 + kk][wc + 4]);
                float w[8] = {w0.x, w0.y, w0.z, w0.w, w1.x, w1.y, w1.z, w1.w};
                #pragma unroll
                for (int j = 0; j < 4; ++j) {
                    float xk = (kk == 0) ? xv[j].x : (kk == 1) ? xv[j].y
                             : (kk == 2) ? xv[j].z : xv[j].w;
                    #pragma unroll
                    for (int i = 0; i < 8; ++i)
                        acc[j][i] = fmaf(xk, w[i], acc[j][i]);
                }
            }
        }
    }

    float* op = (c0 < 64) ? xl : xr;
    const int cc = c0 & 63;
    #pragma unroll
    for (int j = 0; j < 4; ++j) {
        int r = rbase + ty + 16 * j;
        if (r < N) {
            float4 v0 = make_float4(acc[j][0], acc[j][1], acc[j][2], acc[j][3]);
            float4 v1 = make_float4(acc[j][4], acc[j][5], acc[j][6], acc[j][7]);
            *reinterpret_cast<float4*>(&op[(size_t)r * 64 + cc]) = v0;
            *reinterpret_cast<float4*>(&op[(size_t)r * 64 + cc + 4]) = v1;
        }
    }
}

// one wave per destination node; unnormalized softmax (logits bounded in f32);
// unroll-4 to keep 4 gathers in flight.
__global__ __launch_bounds__(256) void gat_kernel(const float* __restrict__ xl,
                                                  const float* __restrict__ xr,
                                                  const int* __restrict__ offs,
                                                  const int* __restrict__ srcs,
                                                  const float* __restrict__ att,
                                                  const float* __restrict__ bias,
                                                  float* __restrict__ out, int N) {
    int lane = threadIdx.x & 63;
    int wid = threadIdx.x >> 6;
    int n = blockIdx.x * 4 + wid;
    if (n >= N) return;
    float att_l = att[lane];
    float b_l = bias[lane];
    float xr_d = xr[(size_t)n * 64 + lane];
    float xls = xl[(size_t)n * 64 + lane];
    float v = xls + xr_d;
    float p = __expf(head_sum16(att_l * fmaxf(v, 0.2f * v)));
    float s0 = p, s1 = 0.f, s2 = 0.f, s3 = 0.f;
    float o0 = xls * p, o1 = 0.f, o2 = 0.f, o3 = 0.f;
    int e0 = offs[n], e1 = offs[n + 1];
    int j = e0;
    for (; j + 3 < e1; j += 4) {
        int sa = srcs[j], sb = srcs[j + 1], sc = srcs[j + 2], sd = srcs[j + 3];
        float xa = xl[(size_t)sa * 64 + lane];
        float xb = xl[(size_t)sb * 64 + lane];
        float xc = xl[(size_t)sc * 64 + lane];
        float xd = xl[(size_t)sd * 64 + lane];
        float ua = xa + xr_d, ub = xb + xr_d, uc = xc + xr_d, ud = xd + xr_d;
        float pa = __expf(head_sum16(att_l * fmaxf(ua, 0.2f * ua)));
        float pb = __expf(head_sum16(att_l * fmaxf(ub, 0.2f * ub)));
        float pc = __expf(head_sum16(att_l * fmaxf(uc, 0.2f * uc)));
        float pd = __expf(head_sum16(att_l * fmaxf(ud, 0.2f * ud)));
        s0 += pa; s1 += pb; s2 += pc; s3 += pd;
        o0 = fmaf(xa, pa, o0);
        o1 = fmaf(xb, pb, o1);
        o2 = fmaf(xc, pc, o2);
        o3 = fmaf(xd, pd, o3);
    }
    for (; j < e1; ++j) {
        int sa = srcs[j];
        float xa = xl[(size_t)sa * 64 + lane];
        float ua = xa + xr_d;
        float pa = __expf(head_sum16(att_l * fmaxf(ua, 0.2f * ua)));
        s1 += pa;
        o1 = fmaf(xa, pa, o1);
    }
    float s = (s0 + s1) + (s2 + s3);
    float o = (o0 + o1) + (o2 + o3);
    out[(size_t)n * 64 + lane] = fmaxf(o / s + b_l, 0.f);
}

extern "C" void kernel_launch(void* const* d_in, const int* in_sizes, int n_in,
                              void* d_out, int out_size, void* d_ws, size_t ws_size,
                              hipStream_t stream) {
    const float* x    = (const float*)d_in[0];
    const int*   edge = (const int*)d_in[1];
    const float* W1l  = (const float*)d_in[2];
    const float* W1r  = (const float*)d_in[3];
    const float* att1 = (const float*)d_in[4];
    const float* b1   = (const float*)d_in[5];
    const float* W2l  = (const float*)d_in[6];
    const float* W2r  = (const float*)d_in[7];
    const float* att2 = (const float*)d_in[8];
    const float* b2   = (const float*)d_in[9];

    const int N = in_sizes[0] / 128;  // 100000
    const int E = in_sizes[1] / 2;    // 1600000
    const int* esrc = edge;
    const int* edst = edge + E;

    char* ws = (char*)d_ws;
    size_t off = 0;
    auto alloc = [&](size_t bytes) {
        void* p = ws + off;
        off += (bytes + 255) & ~(size_t)255;
        return p;
    };
    float* xl     = (float*)alloc((size_t)N * 64 * 4);
    float* xr     = (float*)alloc((size_t)N * 64 * 4);
    float* h      = (float*)alloc((size_t)N * 64 * 4);
    int* deg      = (int*)alloc((size_t)N * 4);
    int* incl     = (int*)alloc((size_t)N * 4);
    int* offs     = (int*)alloc((size_t)(N + 1) * 4);
    int* partials = (int*)alloc(1024 * 4);
    int* srcs     = (int*)alloc((size_t)E * 4);
    u64* pairs    = (u64*)alloc((size_t)E * 8);
    int* gh       = (int*)alloc((size_t)256 * NBLK_S * 4);
    (void)ws_size;

    hipMemsetAsync(deg, 0, (size_t)N * 4, stream);

    const int nblk = (N + 1023) >> 10;
    const int nW = (N + 511) >> 9;  // 196 windows
    hist_kernel<<<1024, 256, 0, stream>>>(edst, deg, E);
    scan_a<<<nblk, 1024, 0, stream>>>(deg, incl, partials, N);
    scan_b<<<1, 1024, 0, stream>>>(partials, nblk);
    scan_c<<<(N + 255) / 256, 256, 0, stream>>>(deg, incl, partials, offs, N, E);
    sort_hist<<<NBLK_S, 256, 0, stream>>>(edst, gh, E, nW);
    sort_scan<<<nW, NBLK_S, 0, stream>>>(offs, gh, N);
    sort_place<<<NBLK_S, 256, 0, stream>>>(esrc, edst, gh, pairs, E, nW);
    window_scatter<<<nW, 256, 0, stream>>>(pairs, offs, srcs, N);

    const int gblk = (N + 63) / 64;
    gemm_lr<128><<<gblk, 256, 0, stream>>>(x, W1l, W1r, xl, xr, N);
    gat_kernel<<<(N + 3) / 4, 256, 0, stream>>>(xl, xr, offs, srcs, att1, b1, h, N);
    gemm_lr<64><<<gblk, 256, 0, stream>>>(h, W2l, W2r, xl, xr, N);
    gat_kernel<<<(N + 3) / 4, 256, 0, stream>>>(xl, xr, offs, srcs, att2, b2, (float*)d_out, N);
}

// Round 6
// 461.550 us; speedup vs baseline: 12.4209x; 1.0227x over previous
//
#include <hip/hip_runtime.h>
#include <hip/hip_bf16.h>

// GATv2 x2 layers, N=100K, E=1.6M (+self loops), H=4, C=16, D=64, F_IN=128, f32.
// CSR build: deg hist + scan -> deterministic radix partition into 512-dst
// windows -> per-window LDS-cursor scatter. Then [tiled gemm -> fused GAT] x 2.
// GAT v3: DPP row_ror head reduction (no DS ops), exp2 with pre-scaled att.

typedef unsigned long long u64;

#define NBLK_S 512  // edge-chunk blocks for the partition passes
#define LOG2E 1.44269504f

// sum over the 16-lane head row via DPP rotate-adds (pure VALU, no LDS)
template <int CTRL>
__device__ __forceinline__ float add_ror(float v) {
    int r = __builtin_amdgcn_update_dpp(0, __float_as_int(v), CTRL, 0xF, 0xF, true);
    return v + __int_as_float(r);
}
__device__ __forceinline__ float head_sum16(float v) {
    v = add_ror<0x121>(v);  // row_ror:1
    v = add_ror<0x122>(v);  // row_ror:2
    v = add_ror<0x124>(v);  // row_ror:4
    v = add_ror<0x128>(v);  // row_ror:8
    return v;
}

__global__ void hist_kernel(const int* __restrict__ dst, int* __restrict__ deg, int E) {
    int i = blockIdx.x * blockDim.x + threadIdx.x;
    int stride = gridDim.x * blockDim.x;
    for (; i < E; i += stride) atomicAdd(&deg[dst[i]], 1);
}

__global__ void scan_a(const int* __restrict__ deg, int* __restrict__ incl,
                       int* __restrict__ partials, int n) {
    __shared__ int sm[2][1024];
    int tid = threadIdx.x;
    int i = blockIdx.x * 1024 + tid;
    int v = (i < n) ? deg[i] : 0;
    sm[0][tid] = v;
    __syncthreads();
    int pin = 0;
    #pragma unroll
    for (int ofs = 1; ofs < 1024; ofs <<= 1) {
        int pout = pin ^ 1;
        sm[pout][tid] = sm[pin][tid] + ((tid >= ofs) ? sm[pin][tid - ofs] : 0);
        pin = pout;
        __syncthreads();
    }
    int r = sm[pin][tid];
    if (i < n) incl[i] = r;
    if (tid == 1023) partials[blockIdx.x] = r;
}

__global__ void scan_b(int* partials, int nblk) {
    __shared__ int sm[2][1024];
    int tid = threadIdx.x;
    int v = (tid < nblk) ? partials[tid] : 0;
    sm[0][tid] = v;
    __syncthreads();
    int pin = 0;
    #pragma unroll
    for (int ofs = 1; ofs < 1024; ofs <<= 1) {
        int pout = pin ^ 1;
        sm[pout][tid] = sm[pin][tid] + ((tid >= ofs) ? sm[pin][tid - ofs] : 0);
        pin = pout;
        __syncthreads();
    }
    if (tid < nblk) partials[tid] = sm[pin][tid] - v;  // exclusive
}

__global__ void scan_c(const int* __restrict__ deg, const int* __restrict__ incl,
                       const int* __restrict__ partials, int* __restrict__ offs,
                       int n, int E) {
    int i = blockIdx.x * blockDim.x + threadIdx.x;
    if (i < n) offs[i] = partials[i >> 10] + incl[i] - deg[i];
    if (i == 0) offs[n] = E;
}

// s1: per-block LDS histogram of 512-dst windows over this block's edge chunk
__global__ __launch_bounds__(256) void sort_hist(const int* __restrict__ edst,
                                                 int* __restrict__ gh, int E, int nW) {
    __shared__ int h[256];
    for (int i = threadIdx.x; i < nW; i += 256) h[i] = 0;
    __syncthreads();
    const int chunk = (E + NBLK_S - 1) / NBLK_S;
    const int lo = blockIdx.x * chunk;
    const int hi = min(E, lo + chunk);
    for (int i = lo + threadIdx.x; i < hi; i += 256)
        atomicAdd(&h[edst[i] >> 9], 1);
    __syncthreads();
    for (int w = threadIdx.x; w < nW; w += 256)
        gh[w * NBLK_S + blockIdx.x] = h[w];
}

// s2: per-window exclusive scan over the 512 block counts (+ window base)
__global__ __launch_bounds__(NBLK_S) void sort_scan(const int* __restrict__ offs,
                                                    int* __restrict__ gh, int N) {
    __shared__ int sm[2][NBLK_S];
    const int w = blockIdx.x;
    const int t = threadIdx.x;
    int v = gh[w * NBLK_S + t];
    sm[0][t] = v;
    __syncthreads();
    int pin = 0;
    #pragma unroll
    for (int ofs = 1; ofs < NBLK_S; ofs <<= 1) {
        int pout = pin ^ 1;
        sm[pout][t] = sm[pin][t] + ((t >= ofs) ? sm[pin][t - ofs] : 0);
        pin = pout;
        __syncthreads();
    }
    gh[w * NBLK_S + t] = offs[w << 9] + sm[pin][t] - v;  // exclusive + base
}

// s3: re-read chunk, place (dst,src) pairs via LDS cursors (no global atomics)
__global__ __launch_bounds__(256) void sort_place(const int* __restrict__ esrc,
                                                  const int* __restrict__ edst,
                                                  const int* __restrict__ gh,
                                                  u64* __restrict__ pairs, int E, int nW) {
    __shared__ int cur[256];
    for (int i = threadIdx.x; i < nW; i += 256)
        cur[i] = gh[i * NBLK_S + blockIdx.x];
    __syncthreads();
    const int chunk = (E + NBLK_S - 1) / NBLK_S;
    const int lo = blockIdx.x * chunk;
    const int hi = min(E, lo + chunk);
    for (int i = lo + threadIdx.x; i < hi; i += 256) {
        int d = edst[i];
        int s = esrc[i];
        int pos = atomicAdd(&cur[d >> 9], 1);
        pairs[pos] = ((u64)(unsigned)d << 32) | (unsigned)s;
    }
}

// s4: one block per window; LDS cursors; writes confined to ~32KB region
__global__ __launch_bounds__(256) void window_scatter(const u64* __restrict__ pairs,
                                                      const int* __restrict__ offs,
                                                      int* __restrict__ srcs, int N) {
    __shared__ int cur[512];
    int w = blockIdx.x;
    int d0 = w << 9;
    int nd = min(512, N - d0);
    for (int i = threadIdx.x; i < nd; i += 256) cur[i] = offs[d0 + i];
    __syncthreads();
    int p0 = offs[d0];
    int p1 = offs[min(d0 + 512, N)];
    for (int idx = p0 + threadIdx.x; idx < p1; idx += 256) {
        u64 pr = pairs[idx];
        int d = (int)(pr >> 32);
        int s = (int)(pr & 0xffffffffu);
        int pos = atomicAdd(&cur[d - d0], 1);
        srcs[pos] = s;
    }
}

// Tiled GEMM: [xl | xr] = X @ [Wl | Wr].  X: [N,K], Wl/Wr: [K,64].
// Block: 64 rows x 128 cols, 256 threads. K-tiled KT=64 (53KB LDS, 3 blk/CU).
#define WIDX(c) ((c) + (((c) >> 5) << 2))
template <int K>
__global__ __launch_bounds__(256) void gemm_lr(const float* __restrict__ X,
                                               const float* __restrict__ Wl,
                                               const float* __restrict__ Wr,
                                               float* __restrict__ xl,
                                               float* __restrict__ xr, int N) {
    constexpr int KT = 64;
    constexpr int LDW = 140;
    constexpr int LDX = KT + 4;  // 68
    __shared__ float Ws[KT][LDW];
    __shared__ float Xs[64][LDX];
    const int tid = threadIdx.x;
    const int rbase = blockIdx.x * 64;
    const int tx = tid & 15;
    const int ty = tid >> 4;
    const int c0 = tx * 8;
    const int wc = WIDX(c0);

    float acc[4][8];
    #pragma unroll
    for (int j = 0; j < 4; ++j)
        #pragma unroll
        for (int i = 0; i < 8; ++i) acc[j][i] = 0.f;

    #pragma unroll
    for (int t = 0; t < K / KT; ++t) {
        if (t) __syncthreads();
        for (int f = tid; f < KT * 16; f += 256) {
            int k = f >> 4;
            int c = (f & 15) << 2;
            float4 a = *reinterpret_cast<const float4*>(&Wl[(size_t)(t * KT + k) * 64 + c]);
            float4 b = *reinterpret_cast<const float4*>(&Wr[(size_t)(t * KT + k) * 64 + c]);
            *reinterpret_cast<float4*>(&Ws[k][WIDX(c)]) = a;
            *reinterpret_cast<float4*>(&Ws[k][WIDX(64 + c)]) = b;
        }
        for (int f = tid; f < 64 * (KT / 4); f += 256) {
            int m = f >> 4;
            int k4 = (f & 15) << 2;
            int r = rbase + m;
            float4 v = (r < N) ? *reinterpret_cast<const float4*>(&X[(size_t)r * K + t * KT + k4])
                               : make_float4(0.f, 0.f, 0.f, 0.f);
            *reinterpret_cast<float4*>(&Xs[m][k4]) = v;
        }
        __syncthreads();

        #pragma unroll 2
        for (int k4 = 0; k4 < KT; k4 += 4) {
            float4 xv[4];
            #pragma unroll
            for (int j = 0; j < 4; ++j)
                xv[j] = *reinterpret_cast<const float4*>(&Xs[ty + 16 * j][k4]);
            #pragma unroll
            for (int kk = 0; kk < 4; ++kk) {
                float4 w0 = *reinterpret_cast<const float4*>(&Ws[k4 + kk][wc]);
                float4 w1 = *reinterpret_cast<const float4*>(&Ws[k4 + kk][wc + 4]);
                float w[8] = {w0.x, w0.y, w0.z, w0.w, w1.x, w1.y, w1.z, w1.w};
                #pragma unroll
                for (int j = 0; j < 4; ++j) {
                    float xk = (kk == 0) ? xv[j].x : (kk == 1) ? xv[j].y
                             : (kk == 2) ? xv[j].z : xv[j].w;
                    #pragma unroll
                    for (int i = 0; i < 8; ++i)
                        acc[j][i] = fmaf(xk, w[i], acc[j][i]);
                }
            }
        }
    }

    float* op = (c0 < 64) ? xl : xr;
    const int cc = c0 & 63;
    #pragma unroll
    for (int j = 0; j < 4; ++j) {
        int r = rbase + ty + 16 * j;
        if (r < N) {
            float4 v0 = make_float4(acc[j][0], acc[j][1], acc[j][2], acc[j][3]);
            float4 v1 = make_float4(acc[j][4], acc[j][5], acc[j][6], acc[j][7]);
            *reinterpret_cast<float4*>(&op[(size_t)r * 64 + cc]) = v0;
            *reinterpret_cast<float4*>(&op[(size_t)r * 64 + cc + 4]) = v1;
        }
    }
}

// one wave per destination node; unnormalized softmax (logits bounded in f32);
// DPP head reduction; exp2 with att pre-scaled by log2(e); unroll-4.
__global__ __launch_bounds__(256) void gat_kernel(const float* __restrict__ xl,
                                                  const float* __restrict__ xr,
                                                  const int* __restrict__ offs,
                                                  const int* __restrict__ srcs,
                                                  const float* __restrict__ att,
                                                  const float* __restrict__ bias,
                                                  float* __restrict__ out, int N) {
    int lane = threadIdx.x & 63;
    int wid = threadIdx.x >> 6;
    int n = blockIdx.x * 4 + wid;
    if (n >= N) return;
    float att_l = att[lane] * LOG2E;   // fold ln->log2 into the weights
    float b_l = bias[lane];
    float xr_d = xr[(size_t)n * 64 + lane];
    float xls = xl[(size_t)n * 64 + lane];
    float v = xls + xr_d;
    float p = exp2f(head_sum16(att_l * fmaxf(v, 0.2f * v)));
    float s0 = p, s1 = 0.f, s2 = 0.f, s3 = 0.f;
    float o0 = xls * p, o1 = 0.f, o2 = 0.f, o3 = 0.f;
    int e0 = offs[n], e1 = offs[n + 1];
    int j = e0;
    for (; j + 3 < e1; j += 4) {
        int sa = srcs[j], sb = srcs[j + 1], sc = srcs[j + 2], sd = srcs[j + 3];
        float xa = xl[(size_t)sa * 64 + lane];
        float xb = xl[(size_t)sb * 64 + lane];
        float xc = xl[(size_t)sc * 64 + lane];
        float xd = xl[(size_t)sd * 64 + lane];
        float ua = xa + xr_d, ub = xb + xr_d, uc = xc + xr_d, ud = xd + xr_d;
        float pa = exp2f(head_sum16(att_l * fmaxf(ua, 0.2f * ua)));
        float pb = exp2f(head_sum16(att_l * fmaxf(ub, 0.2f * ub)));
        float pc = exp2f(head_sum16(att_l * fmaxf(uc, 0.2f * uc)));
        float pd = exp2f(head_sum16(att_l * fmaxf(ud, 0.2f * ud)));
        s0 += pa; s1 += pb; s2 += pc; s3 += pd;
        o0 = fmaf(xa, pa, o0);
        o1 = fmaf(xb, pb, o1);
        o2 = fmaf(xc, pc, o2);
        o3 = fmaf(xd, pd, o3);
    }
    for (; j < e1; ++j) {
        int sa = srcs[j];
        float xa = xl[(size_t)sa * 64 + lane];
        float ua = xa + xr_d;
        float pa = exp2f(head_sum16(att_l * fmaxf(ua, 0.2f * ua)));
        s1 += pa;
        o1 = fmaf(xa, pa, o1);
    }
    float s = (s0 + s1) + (s2 + s3);
    float o = (o0 + o1) + (o2 + o3);
    out[(size_t)n * 64 + lane] = fmaxf(o / s + b_l, 0.f);
}

extern "C" void kernel_launch(void* const* d_in, const int* in_sizes, int n_in,
                              void* d_out, int out_size, void* d_ws, size_t ws_size,
                              hipStream_t stream) {
    const float* x    = (const float*)d_in[0];
    const int*   edge = (const int*)d_in[1];
    const float* W1l  = (const float*)d_in[2];
    const float* W1r  = (const float*)d_in[3];
    const float* att1 = (const float*)d_in[4];
    const float* b1   = (const float*)d_in[5];
    const float* W2l  = (const float*)d_in[6];
    const float* W2r  = (const float*)d_in[7];
    const float* att2 = (const float*)d_in[8];
    const float* b2   = (const float*)d_in[9];

    const int N = in_sizes[0] / 128;  // 100000
    const int E = in_sizes[1] / 2;    // 1600000
    const int* esrc = edge;
    const int* edst = edge + E;

    char* ws = (char*)d_ws;
    size_t off = 0;
    auto alloc = [&](size_t bytes) {
        void* p = ws + off;
        off += (bytes + 255) & ~(size_t)255;
        return p;
    };
    float* xl     = (float*)alloc((size_t)N * 64 * 4);
    float* xr     = (float*)alloc((size_t)N * 64 * 4);
    float* h      = (float*)alloc((size_t)N * 64 * 4);
    int* deg      = (int*)alloc((size_t)N * 4);
    int* incl     = (int*)alloc((size_t)N * 4);
    int* offs     = (int*)alloc((size_t)(N + 1) * 4);
    int* partials = (int*)alloc(1024 * 4);
    int* srcs     = (int*)alloc((size_t)E * 4);
    u64* pairs    = (u64*)alloc((size_t)E * 8);
    int* gh       = (int*)alloc((size_t)256 * NBLK_S * 4);
    (void)ws_size;

    hipMemsetAsync(deg, 0, (size_t)N * 4, stream);

    const int nblk = (N + 1023) >> 10;
    const int nW = (N + 511) >> 9;  // 196 windows
    hist_kernel<<<1024, 256, 0, stream>>>(edst, deg, E);
    scan_a<<<nblk, 1024, 0, stream>>>(deg, incl, partials, N);
    scan_b<<<1, 1024, 0, stream>>>(partials, nblk);
    scan_c<<<(N + 255) / 256, 256, 0, stream>>>(deg, incl, partials, offs, N, E);
    sort_hist<<<NBLK_S, 256, 0, stream>>>(edst, gh, E, nW);
    sort_scan<<<nW, NBLK_S, 0, stream>>>(offs, gh, N);
    sort_place<<<NBLK_S, 256, 0, stream>>>(esrc, edst, gh, pairs, E, nW);
    window_scatter<<<nW, 256, 0, stream>>>(pairs, offs, srcs, N);

    const int gblk = (N + 63) / 64;
    gemm_lr<128><<<gblk, 256, 0, stream>>>(x, W1l, W1r, xl, xr, N);
    gat_kernel<<<(N + 3) / 4, 256, 0, stream>>>(xl, xr, offs, srcs, att1, b1, h, N);
    gemm_lr<64><<<gblk, 256, 0, stream>>>(h, W2l, W2r, xl, xr, N);
    gat_kernel<<<(N + 3) / 4, 256, 0, stream>>>(xl, xr, offs, srcs, att2, b2, (float*)d_out, N);
}

// Round 7
// 460.560 us; speedup vs baseline: 12.4476x; 1.0021x over previous
//
#include <hip/hip_runtime.h>
#include <hip/hip_bf16.h>

// GATv2 x2 layers, N=100K, E=1.6M (+self loops), H=4, C=16, D=64, F_IN=128, f32.
// CSR build: fused deg+window hist (1 edge pass) -> scans -> [sort_place || gemm128-A]
// -> [window_scatter || gemm128-B] -> gat1 -> gemm64 -> gat2.
// GAT v4: pre-shifted src offsets, int4 src loads, 2-op leaky (0.6a*u + 0.4a*|u|),
// DPP head reduction, exp2 with pre-scaled att.

typedef unsigned long long u64;

#define NBLK_S 512  // edge-chunk blocks for the partition passes
#define LOG2E 1.44269504f

// sum over the 16-lane head row via DPP rotate-adds (pure VALU, no LDS)
template <int CTRL>
__device__ __forceinline__ float add_ror(float v) {
    int r = __builtin_amdgcn_update_dpp(0, __float_as_int(v), CTRL, 0xF, 0xF, true);
    return v + __int_as_float(r);
}
__device__ __forceinline__ float head_sum16(float v) {
    v = add_ror<0x121>(v);  // row_ror:1
    v = add_ror<0x122>(v);  // row_ror:2
    v = add_ror<0x124>(v);  // row_ror:4
    v = add_ror<0x128>(v);  // row_ror:8
    return v;
}

// fused: per-node degree (global atomics) + per-window LDS hist, one edge pass
__global__ __launch_bounds__(256) void hist_fused(const int* __restrict__ edst,
                                                  int* __restrict__ deg,
                                                  int* __restrict__ gh, int E, int nW) {
    __shared__ int h[256];
    for (int i = threadIdx.x; i < 256; i += 256) h[i] = 0;
    __syncthreads();
    const int chunk = (E + NBLK_S - 1) / NBLK_S;
    const int lo = blockIdx.x * chunk;
    const int hi = min(E, lo + chunk);
    for (int i = lo + threadIdx.x; i < hi; i += 256) {
        int d = edst[i];
        atomicAdd(&deg[d], 1);
        atomicAdd(&h[d >> 9], 1);
    }
    __syncthreads();
    for (int w = threadIdx.x; w < nW; w += 256)
        gh[w * NBLK_S + blockIdx.x] = h[w];
}

__global__ void scan_a(const int* __restrict__ deg, int* __restrict__ incl,
                       int* __restrict__ partials, int n) {
    __shared__ int sm[2][1024];
    int tid = threadIdx.x;
    int i = blockIdx.x * 1024 + tid;
    int v = (i < n) ? deg[i] : 0;
    sm[0][tid] = v;
    __syncthreads();
    int pin = 0;
    #pragma unroll
    for (int ofs = 1; ofs < 1024; ofs <<= 1) {
        int pout = pin ^ 1;
        sm[pout][tid] = sm[pin][tid] + ((tid >= ofs) ? sm[pin][tid - ofs] : 0);
        pin = pout;
        __syncthreads();
    }
    int r = sm[pin][tid];
    if (i < n) incl[i] = r;
    if (tid == 1023) partials[blockIdx.x] = r;
}

__global__ void scan_b(int* partials, int nblk) {
    __shared__ int sm[2][1024];
    int tid = threadIdx.x;
    int v = (tid < nblk) ? partials[tid] : 0;
    sm[0][tid] = v;
    __syncthreads();
    int pin = 0;
    #pragma unroll
    for (int ofs = 1; ofs < 1024; ofs <<= 1) {
        int pout = pin ^ 1;
        sm[pout][tid] = sm[pin][tid] + ((tid >= ofs) ? sm[pin][tid - ofs] : 0);
        pin = pout;
        __syncthreads();
    }
    if (tid < nblk) partials[tid] = sm[pin][tid] - v;  // exclusive
}

__global__ void scan_c(const int* __restrict__ deg, const int* __restrict__ incl,
                       const int* __restrict__ partials, int* __restrict__ offs,
                       int n, int E) {
    int i = blockIdx.x * blockDim.x + threadIdx.x;
    if (i < n) offs[i] = partials[i >> 10] + incl[i] - deg[i];
    if (i == 0) offs[n] = E;
}

// per-window exclusive scan over the 512 block counts (+ window base)
__global__ __launch_bounds__(NBLK_S) void sort_scan(const int* __restrict__ offs,
                                                    int* __restrict__ gh, int N) {
    __shared__ int sm[2][NBLK_S];
    const int w = blockIdx.x;
    const int t = threadIdx.x;
    int v = gh[w * NBLK_S + t];
    sm[0][t] = v;
    __syncthreads();
    int pin = 0;
    #pragma unroll
    for (int ofs = 1; ofs < NBLK_S; ofs <<= 1) {
        int pout = pin ^ 1;
        sm[pout][t] = sm[pin][t] + ((t >= ofs) ? sm[pin][t - ofs] : 0);
        pin = pout;
        __syncthreads();
    }
    gh[w * NBLK_S + t] = offs[w << 9] + sm[pin][t] - v;  // exclusive + base
}

// ---------------- GEMM device body (shared by fused + standalone kernels) ----
// [xl | xr] = X @ [Wl | Wr].  Block: 64 rows x 128 cols, 256 threads.
// K-tiled KT=64 (52KB LDS, 3 blk/CU). Rows ty+{0,16,32,48}: conflict-free Xs.
#define WIDX(c) ((c) + (((c) >> 5) << 2))
#define GEMM_LDS_FLOATS (64 * 140 + 64 * 68)  // Ws + Xs = 13312 floats = 52KB

template <int K>
__device__ __forceinline__ void gemm_body(int rbase, const float* __restrict__ X,
                                          const float* __restrict__ Wl,
                                          const float* __restrict__ Wr,
                                          float* __restrict__ xl,
                                          float* __restrict__ xr, int N,
                                          float* __restrict__ sm) {
    constexpr int KT = 64;
    constexpr int LDW = 140;
    constexpr int LDX = KT + 4;  // 68
    float* Ws = sm;              // [KT][LDW]
    float* Xs = sm + KT * LDW;   // [64][LDX]
    const int tid = threadIdx.x;
    const int tx = tid & 15;
    const int ty = tid >> 4;
    const int c0 = tx * 8;
    const int wc = WIDX(c0);

    float acc[4][8];
    #pragma unroll
    for (int j = 0; j < 4; ++j)
        #pragma unroll
        for (int i = 0; i < 8; ++i) acc[j][i] = 0.f;

    #pragma unroll
    for (int t = 0; t < K / KT; ++t) {
        if (t) __syncthreads();
        for (int f = tid; f < KT * 16; f += 256) {
            int k = f >> 4;
            int c = (f & 15) << 2;
            float4 a = *reinterpret_cast<const float4*>(&Wl[(size_t)(t * KT + k) * 64 + c]);
            float4 b = *reinterpret_cast<const float4*>(&Wr[(size_t)(t * KT + k) * 64 + c]);
            *reinterpret_cast<float4*>(&Ws[k * LDW + WIDX(c)]) = a;
            *reinterpret_cast<float4*>(&Ws[k * LDW + WIDX(64 + c)]) = b;
        }
        for (int f = tid; f < 64 * (KT / 4); f += 256) {
            int m = f >> 4;
            int k4 = (f & 15) << 2;
            int r = rbase + m;
            float4 v = (r < N) ? *reinterpret_cast<const float4*>(&X[(size_t)r * K + t * KT + k4])
                               : make_float4(0.f, 0.f, 0.f, 0.f);
            *reinterpret_cast<float4*>(&Xs[m * LDX + k4]) = v;
        }
        __syncthreads();

        #pragma unroll 2
        for (int k4 = 0; k4 < KT; k4 += 4) {
            float4 xv[4];
            #pragma unroll
            for (int j = 0; j < 4; ++j)
                xv[j] = *reinterpret_cast<const float4*>(&Xs[(ty + 16 * j) * LDX + k4]);
            #pragma unroll
            for (int kk = 0; kk < 4; ++kk) {
                float4 w0 = *reinterpret_cast<const float4*>(&Ws[(k4 + kk) * LDW + wc]);
                float4 w1 = *reinterpret_cast<const float4*>(&Ws[(k4 + kk) * LDW + wc + 4]);
                float w[8] = {w0.x, w0.y, w0.z, w0.w, w1.x, w1.y, w1.z, w1.w};
                #pragma unroll
                for (int j = 0; j < 4; ++j) {
                    float xk = (kk == 0) ? xv[j].x : (kk == 1) ? xv[j].y
                             : (kk == 2) ? xv[j].z : xv[j].w;
                    #pragma unroll
                    for (int i = 0; i < 8; ++i)
                        acc[j][i] = fmaf(xk, w[i], acc[j][i]);
                }
            }
        }
    }

    float* op = (c0 < 64) ? xl : xr;
    const int cc = c0 & 63;
    #pragma unroll
    for (int j = 0; j < 4; ++j) {
        int r = rbase + ty + 16 * j;
        if (r < N) {
            float4 v0 = make_float4(acc[j][0], acc[j][1], acc[j][2], acc[j][3]);
            float4 v1 = make_float4(acc[j][4], acc[j][5], acc[j][6], acc[j][7]);
            *reinterpret_cast<float4*>(&op[(size_t)r * 64 + cc]) = v0;
            *reinterpret_cast<float4*>(&op[(size_t)r * 64 + cc + 4]) = v1;
        }
    }
}

// fused: blocks [0,placeBlocks) run sort_place; rest run gemm128 chunk A.
// sort_place: re-read edge chunk, place u32 (doff<<17|src) via LDS cursors.
__global__ __launch_bounds__(256) void place_gemm(const int* __restrict__ esrc,
                                                  const int* __restrict__ edst,
                                                  const int* __restrict__ gh,
                                                  unsigned* __restrict__ pairs,
                                                  int E, int nW,
                                                  const float* __restrict__ X,
                                                  const float* __restrict__ Wl,
                                                  const float* __restrict__ Wr,
                                                  float* __restrict__ xl,
                                                  float* __restrict__ xr, int N) {
    __shared__ float sm[GEMM_LDS_FLOATS];
    if (blockIdx.x < NBLK_S) {
        int* cur = (int*)sm;
        const int bid = blockIdx.x;
        for (int i = threadIdx.x; i < nW; i += 256)
            cur[i] = gh[i * NBLK_S + bid];
        __syncthreads();
        const int chunk = (E + NBLK_S - 1) / NBLK_S;
        const int lo = bid * chunk;
        const int hi = min(E, lo + chunk);
        for (int i = lo + threadIdx.x; i < hi; i += 256) {
            int d = edst[i];
            int s = esrc[i];
            int pos = atomicAdd(&cur[d >> 9], 1);
            pairs[pos] = ((unsigned)(d & 511) << 17) | (unsigned)s;
        }
    } else {
        gemm_body<128>((blockIdx.x - NBLK_S) * 64, X, Wl, Wr, xl, xr, N, sm);
    }
}

// fused: blocks [0,nW) run window_scatter; rest run gemm128 chunk B.
// window_scatter: LDS cursors over 512 dsts; writes pre-shifted src offsets.
__global__ __launch_bounds__(256) void scatter_gemm(const unsigned* __restrict__ pairs,
                                                    const int* __restrict__ offs,
                                                    int* __restrict__ srcs, int nW, int gemmBase,
                                                    const float* __restrict__ X,
                                                    const float* __restrict__ Wl,
                                                    const float* __restrict__ Wr,
                                                    float* __restrict__ xl,
                                                    float* __restrict__ xr, int N) {
    __shared__ float sm[GEMM_LDS_FLOATS];
    if ((int)blockIdx.x < nW) {
        int* cur = (int*)sm;
        int w = blockIdx.x;
        int d0 = w << 9;
        int nd = min(512, N - d0);
        for (int i = threadIdx.x; i < nd; i += 256) cur[i] = offs[d0 + i];
        __syncthreads();
        int p0 = offs[d0];
        int p1 = offs[min(d0 + 512, N)];
        for (int idx = p0 + threadIdx.x; idx < p1; idx += 256) {
            unsigned pr = pairs[idx];
            int doff = (int)(pr >> 17);
            int s = (int)(pr & 0x1FFFFu);
            int pos = atomicAdd(&cur[doff], 1);
            srcs[pos] = s << 6;  // pre-shifted row offset for the gat gather
        }
    } else {
        gemm_body<128>((gemmBase + blockIdx.x - nW) * 64, X, Wl, Wr, xl, xr, N, sm);
    }
}

// standalone gemm (layer 2, K=64)
template <int K>
__global__ __launch_bounds__(256) void gemm_lr(const float* __restrict__ X,
                                               const float* __restrict__ Wl,
                                               const float* __restrict__ Wr,
                                               float* __restrict__ xl,
                                               float* __restrict__ xr, int N) {
    __shared__ float sm[GEMM_LDS_FLOATS];
    gemm_body<K>(blockIdx.x * 64, X, Wl, Wr, xl, xr, N, sm);
}

// one wave per destination node; unnormalized softmax (logits bounded in f32).
// srcs holds pre-shifted row offsets (src*64); int4 quad loads; 2-op leaky:
// a*leaky(u) = 0.6a*u + 0.4a*|u| (abs = free input modifier). exp2-domain att.
__global__ __launch_bounds__(256) void gat_kernel(const float* __restrict__ xl,
                                                  const float* __restrict__ xr,
                                                  const int* __restrict__ offs,
                                                  const int* __restrict__ srcs,
                                                  const float* __restrict__ att,
                                                  const float* __restrict__ bias,
                                                  float* __restrict__ out, int N) {
    int lane = threadIdx.x & 63;
    int wid = threadIdx.x >> 6;
    int n = blockIdx.x * 4 + wid;
    if (n >= N) return;
    float a_l = att[lane] * LOG2E;
    float a1 = 0.6f * a_l;
    float a2 = 0.4f * a_l;
    float b_l = bias[lane];
    unsigned bn = (unsigned)n * 64u + (unsigned)lane;
    float xr_d = xr[bn];
    float xls = xl[bn];
    float u = xls + xr_d;
    float p = exp2f(head_sum16(fmaf(a1, u, a2 * fabsf(u))));
    float s0 = p, s1 = 0.f, s2 = 0.f, s3 = 0.f;
    float o0 = xls * p, o1 = 0.f, o2 = 0.f, o3 = 0.f;
    int e0 = offs[n], e1 = offs[n + 1];
    int j = e0;
    int ja = min((e0 + 3) & ~3, e1);  // align for int4 loads
    for (; j < ja; ++j) {
        unsigned off = (unsigned)srcs[j] + lane;
        float xa = xl[off];
        float ua = xa + xr_d;
        float pa = exp2f(head_sum16(fmaf(a1, ua, a2 * fabsf(ua))));
        s1 += pa;
        o1 = fmaf(xa, pa, o1);
    }
    for (; j + 3 < e1; j += 4) {
        int4 q = *reinterpret_cast<const int4*>(&srcs[j]);
        float xa = xl[(unsigned)q.x + lane];
        float xb = xl[(unsigned)q.y + lane];
        float xc = xl[(unsigned)q.z + lane];
        float xd = xl[(unsigned)q.w + lane];
        float ua = xa + xr_d, ub = xb + xr_d, uc = xc + xr_d, ud = xd + xr_d;
        float pa = exp2f(head_sum16(fmaf(a1, ua, a2 * fabsf(ua))));
        float pb = exp2f(head_sum16(fmaf(a1, ub, a2 * fabsf(ub))));
        float pc = exp2f(head_sum16(fmaf(a1, uc, a2 * fabsf(uc))));
        float pd = exp2f(head_sum16(fmaf(a1, ud, a2 * fabsf(ud))));
        s0 += pa; s1 += pb; s2 += pc; s3 += pd;
        o0 = fmaf(xa, pa, o0);
        o1 = fmaf(xb, pb, o1);
        o2 = fmaf(xc, pc, o2);
        o3 = fmaf(xd, pd, o3);
    }
    for (; j < e1; ++j) {
        unsigned off = (unsigned)srcs[j] + lane;
        float xa = xl[off];
        float ua = xa + xr_d;
        float pa = exp2f(head_sum16(fmaf(a1, ua, a2 * fabsf(ua))));
        s1 += pa;
        o1 = fmaf(xa, pa, o1);
    }
    float s = (s0 + s1) + (s2 + s3);
    float o = (o0 + o1) + (o2 + o3);
    out[bn] = fmaxf(o / s + b_l, 0.f);
}

extern "C" void kernel_launch(void* const* d_in, const int* in_sizes, int n_in,
                              void* d_out, int out_size, void* d_ws, size_t ws_size,
                              hipStream_t stream) {
    const float* x    = (const float*)d_in[0];
    const int*   edge = (const int*)d_in[1];
    const float* W1l  = (const float*)d_in[2];
    const float* W1r  = (const float*)d_in[3];
    const float* att1 = (const float*)d_in[4];
    const float* b1   = (const float*)d_in[5];
    const float* W2l  = (const float*)d_in[6];
    const float* W2r  = (const float*)d_in[7];
    const float* att2 = (const float*)d_in[8];
    const float* b2   = (const float*)d_in[9];

    const int N = in_sizes[0] / 128;  // 100000
    const int E = in_sizes[1] / 2;    // 1600000
    const int* esrc = edge;
    const int* edst = edge + E;

    char* ws = (char*)d_ws;
    size_t off = 0;
    auto alloc = [&](size_t bytes) {
        void* p = ws + off;
        off += (bytes + 255) & ~(size_t)255;
        return p;
    };
    float* xl     = (float*)alloc((size_t)N * 64 * 4);
    float* xr     = (float*)alloc((size_t)N * 64 * 4);
    float* h      = (float*)alloc((size_t)N * 64 * 4);
    int* deg      = (int*)alloc((size_t)N * 4);
    int* incl     = (int*)alloc((size_t)N * 4);
    int* offs     = (int*)alloc((size_t)(N + 1) * 4);
    int* partials = (int*)alloc(1024 * 4);
    int* srcs     = (int*)alloc((size_t)E * 4);
    unsigned* pairs = (unsigned*)alloc((size_t)E * 4);
    int* gh       = (int*)alloc((size_t)256 * NBLK_S * 4);
    (void)ws_size;

    hipMemsetAsync(deg, 0, (size_t)N * 4, stream);

    const int nblk = (N + 1023) >> 10;
    const int nW = (N + 511) >> 9;           // 196 windows
    const int gblk = (N + 63) / 64;          // 1563 gemm blocks
    const int GA = gblk / 2;                 // gemm chunk A (with place)
    const int GB = gblk - GA;                // gemm chunk B (with scatter)

    hist_fused<<<NBLK_S, 256, 0, stream>>>(edst, deg, gh, E, nW);
    scan_a<<<nblk, 1024, 0, stream>>>(deg, incl, partials, N);
    scan_b<<<1, 1024, 0, stream>>>(partials, nblk);
    scan_c<<<(N + 255) / 256, 256, 0, stream>>>(deg, incl, partials, offs, N, E);
    sort_scan<<<nW, NBLK_S, 0, stream>>>(offs, gh, N);
    place_gemm<<<NBLK_S + GA, 256, 0, stream>>>(esrc, edst, gh, pairs, E, nW,
                                                x, W1l, W1r, xl, xr, N);
    scatter_gemm<<<nW + GB, 256, 0, stream>>>(pairs, offs, srcs, nW, GA,
                                              x, W1l, W1r, xl, xr, N);
    gat_kernel<<<(N + 3) / 4, 256, 0, stream>>>(xl, xr, offs, srcs, att1, b1, h, N);
    gemm_lr<64><<<gblk, 256, 0, stream>>>(h, W2l, W2r, xl, xr, N);
    gat_kernel<<<(N + 3) / 4, 256, 0, stream>>>(xl, xr, offs, srcs, att2, b2, (float*)d_out, N);
}

// Round 8
// 436.035 us; speedup vs baseline: 13.1477x; 1.0562x over previous
//
#include <hip/hip_runtime.h>
#include <hip/hip_bf16.h>

// GATv2 x2 layers, N=100K, E=1.6M (+self loops), H=4, C=16, D=64, F_IN=128, f32.
// CSR build: fused deg+window hist -> scans -> [sort_place || gemm128-A]
// -> [window_scatter || gemm128-B] -> gat1 -> gemm64 -> gat2.
// GAT v5: 4 edges/wave x 16 lanes/edge x float4/lane gathers; quad-DPP logit
// reduce; cross-group shfl epilogue; 2-op leaky; exp2-domain att.

typedef unsigned long long u64;

#define NBLK_S 512  // edge-chunk blocks for the partition passes
#define LOG2E 1.44269504f

// sum within aligned 4-lane quad (DPP quad_perm, pure VALU)
__device__ __forceinline__ float quad_sum4(float v) {
    int r1 = __builtin_amdgcn_update_dpp(0, __float_as_int(v), 0xB1, 0xF, 0xF, true);
    v += __int_as_float(r1);
    int r2 = __builtin_amdgcn_update_dpp(0, __float_as_int(v), 0x4E, 0xF, 0xF, true);
    v += __int_as_float(r2);
    return v;
}

// fused: per-node degree (global atomics) + per-window LDS hist, one edge pass
__global__ __launch_bounds__(256) void hist_fused(const int* __restrict__ edst,
                                                  int* __restrict__ deg,
                                                  int* __restrict__ gh, int E, int nW) {
    __shared__ int h[256];
    for (int i = threadIdx.x; i < 256; i += 256) h[i] = 0;
    __syncthreads();
    const int chunk = (E + NBLK_S - 1) / NBLK_S;
    const int lo = blockIdx.x * chunk;
    const int hi = min(E, lo + chunk);
    for (int i = lo + threadIdx.x; i < hi; i += 256) {
        int d = edst[i];
        atomicAdd(&deg[d], 1);
        atomicAdd(&h[d >> 9], 1);
    }
    __syncthreads();
    for (int w = threadIdx.x; w < nW; w += 256)
        gh[w * NBLK_S + blockIdx.x] = h[w];
}

__global__ void scan_a(const int* __restrict__ deg, int* __restrict__ incl,
                       int* __restrict__ partials, int n) {
    __shared__ int sm[2][1024];
    int tid = threadIdx.x;
    int i = blockIdx.x * 1024 + tid;
    int v = (i < n) ? deg[i] : 0;
    sm[0][tid] = v;
    __syncthreads();
    int pin = 0;
    #pragma unroll
    for (int ofs = 1; ofs < 1024; ofs <<= 1) {
        int pout = pin ^ 1;
        sm[pout][tid] = sm[pin][tid] + ((tid >= ofs) ? sm[pin][tid - ofs] : 0);
        pin = pout;
        __syncthreads();
    }
    int r = sm[pin][tid];
    if (i < n) incl[i] = r;
    if (tid == 1023) partials[blockIdx.x] = r;
}

__global__ void scan_b(int* partials, int nblk) {
    __shared__ int sm[2][1024];
    int tid = threadIdx.x;
    int v = (tid < nblk) ? partials[tid] : 0;
    sm[0][tid] = v;
    __syncthreads();
    int pin = 0;
    #pragma unroll
    for (int ofs = 1; ofs < 1024; ofs <<= 1) {
        int pout = pin ^ 1;
        sm[pout][tid] = sm[pin][tid] + ((tid >= ofs) ? sm[pin][tid - ofs] : 0);
        pin = pout;
        __syncthreads();
    }
    if (tid < nblk) partials[tid] = sm[pin][tid] - v;  // exclusive
}

__global__ void scan_c(const int* __restrict__ deg, const int* __restrict__ incl,
                       const int* __restrict__ partials, int* __restrict__ offs,
                       int n, int E) {
    int i = blockIdx.x * blockDim.x + threadIdx.x;
    if (i < n) offs[i] = partials[i >> 10] + incl[i] - deg[i];
    if (i == 0) offs[n] = E;
}

// per-window exclusive scan over the 512 block counts (+ window base)
__global__ __launch_bounds__(NBLK_S) void sort_scan(const int* __restrict__ offs,
                                                    int* __restrict__ gh, int N) {
    __shared__ int sm[2][NBLK_S];
    const int w = blockIdx.x;
    const int t = threadIdx.x;
    int v = gh[w * NBLK_S + t];
    sm[0][t] = v;
    __syncthreads();
    int pin = 0;
    #pragma unroll
    for (int ofs = 1; ofs < NBLK_S; ofs <<= 1) {
        int pout = pin ^ 1;
        sm[pout][t] = sm[pin][t] + ((t >= ofs) ? sm[pin][t - ofs] : 0);
        pin = pout;
        __syncthreads();
    }
    gh[w * NBLK_S + t] = offs[w << 9] + sm[pin][t] - v;  // exclusive + base
}

// ---------------- GEMM device body (shared by fused + standalone kernels) ----
#define WIDX(c) ((c) + (((c) >> 5) << 2))
#define GEMM_LDS_FLOATS (64 * 140 + 64 * 68)  // Ws + Xs = 13312 floats = 52KB

template <int K>
__device__ __forceinline__ void gemm_body(int rbase, const float* __restrict__ X,
                                          const float* __restrict__ Wl,
                                          const float* __restrict__ Wr,
                                          float* __restrict__ xl,
                                          float* __restrict__ xr, int N,
                                          float* __restrict__ sm) {
    constexpr int KT = 64;
    constexpr int LDW = 140;
    constexpr int LDX = KT + 4;  // 68
    float* Ws = sm;              // [KT][LDW]
    float* Xs = sm + KT * LDW;   // [64][LDX]
    const int tid = threadIdx.x;
    const int tx = tid & 15;
    const int ty = tid >> 4;
    const int c0 = tx * 8;
    const int wc = WIDX(c0);

    float acc[4][8];
    #pragma unroll
    for (int j = 0; j < 4; ++j)
        #pragma unroll
        for (int i = 0; i < 8; ++i) acc[j][i] = 0.f;

    #pragma unroll
    for (int t = 0; t < K / KT; ++t) {
        if (t) __syncthreads();
        for (int f = tid; f < KT * 16; f += 256) {
            int k = f >> 4;
            int c = (f & 15) << 2;
            float4 a = *reinterpret_cast<const float4*>(&Wl[(size_t)(t * KT + k) * 64 + c]);
            float4 b = *reinterpret_cast<const float4*>(&Wr[(size_t)(t * KT + k) * 64 + c]);
            *reinterpret_cast<float4*>(&Ws[k * LDW + WIDX(c)]) = a;
            *reinterpret_cast<float4*>(&Ws[k * LDW + WIDX(64 + c)]) = b;
        }
        for (int f = tid; f < 64 * (KT / 4); f += 256) {
            int m = f >> 4;
            int k4 = (f & 15) << 2;
            int r = rbase + m;
            float4 v = (r < N) ? *reinterpret_cast<const float4*>(&X[(size_t)r * K + t * KT + k4])
                               : make_float4(0.f, 0.f, 0.f, 0.f);
            *reinterpret_cast<float4*>(&Xs[m * LDX + k4]) = v;
        }
        __syncthreads();

        #pragma unroll 2
        for (int k4 = 0; k4 < KT; k4 += 4) {
            float4 xv[4];
            #pragma unroll
            for (int j = 0; j < 4; ++j)
                xv[j] = *reinterpret_cast<const float4*>(&Xs[(ty + 16 * j) * LDX + k4]);
            #pragma unroll
            for (int kk = 0; kk < 4; ++kk) {
                float4 w0 = *reinterpret_cast<const float4*>(&Ws[(k4 + kk) * LDW + wc]);
                float4 w1 = *reinterpret_cast<const float4*>(&Ws[(k4 + kk) * LDW + wc + 4]);
                float w[8] = {w0.x, w0.y, w0.z, w0.w, w1.x, w1.y, w1.z, w1.w};
                #pragma unroll
                for (int j = 0; j < 4; ++j) {
                    float xk = (kk == 0) ? xv[j].x : (kk == 1) ? xv[j].y
                             : (kk == 2) ? xv[j].z : xv[j].w;
                    #pragma unroll
                    for (int i = 0; i < 8; ++i)
                        acc[j][i] = fmaf(xk, w[i], acc[j][i]);
                }
            }
        }
    }

    float* op = (c0 < 64) ? xl : xr;
    const int cc = c0 & 63;
    #pragma unroll
    for (int j = 0; j < 4; ++j) {
        int r = rbase + ty + 16 * j;
        if (r < N) {
            float4 v0 = make_float4(acc[j][0], acc[j][1], acc[j][2], acc[j][3]);
            float4 v1 = make_float4(acc[j][4], acc[j][5], acc[j][6], acc[j][7]);
            *reinterpret_cast<float4*>(&op[(size_t)r * 64 + cc]) = v0;
            *reinterpret_cast<float4*>(&op[(size_t)r * 64 + cc + 4]) = v1;
        }
    }
}

// fused: blocks [0,NBLK_S) run sort_place; rest run gemm128 chunk A.
__global__ __launch_bounds__(256) void place_gemm(const int* __restrict__ esrc,
                                                  const int* __restrict__ edst,
                                                  const int* __restrict__ gh,
                                                  unsigned* __restrict__ pairs,
                                                  int E, int nW,
                                                  const float* __restrict__ X,
                                                  const float* __restrict__ Wl,
                                                  const float* __restrict__ Wr,
                                                  float* __restrict__ xl,
                                                  float* __restrict__ xr, int N) {
    __shared__ float sm[GEMM_LDS_FLOATS];
    if (blockIdx.x < NBLK_S) {
        int* cur = (int*)sm;
        const int bid = blockIdx.x;
        for (int i = threadIdx.x; i < nW; i += 256)
            cur[i] = gh[i * NBLK_S + bid];
        __syncthreads();
        const int chunk = (E + NBLK_S - 1) / NBLK_S;
        const int lo = bid * chunk;
        const int hi = min(E, lo + chunk);
        for (int i = lo + threadIdx.x; i < hi; i += 256) {
            int d = edst[i];
            int s = esrc[i];
            int pos = atomicAdd(&cur[d >> 9], 1);
            pairs[pos] = ((unsigned)(d & 511) << 17) | (unsigned)s;
        }
    } else {
        gemm_body<128>((blockIdx.x - NBLK_S) * 64, X, Wl, Wr, xl, xr, N, sm);
    }
}

// fused: blocks [0,nW) run window_scatter; rest run gemm128 chunk B.
__global__ __launch_bounds__(256) void scatter_gemm(const unsigned* __restrict__ pairs,
                                                    const int* __restrict__ offs,
                                                    int* __restrict__ srcs, int nW, int gemmBase,
                                                    const float* __restrict__ X,
                                                    const float* __restrict__ Wl,
                                                    const float* __restrict__ Wr,
                                                    float* __restrict__ xl,
                                                    float* __restrict__ xr, int N) {
    __shared__ float sm[GEMM_LDS_FLOATS];
    if ((int)blockIdx.x < nW) {
        int* cur = (int*)sm;
        int w = blockIdx.x;
        int d0 = w << 9;
        int nd = min(512, N - d0);
        for (int i = threadIdx.x; i < nd; i += 256) cur[i] = offs[d0 + i];
        __syncthreads();
        int p0 = offs[d0];
        int p1 = offs[min(d0 + 512, N)];
        for (int idx = p0 + threadIdx.x; idx < p1; idx += 256) {
            unsigned pr = pairs[idx];
            int doff = (int)(pr >> 17);
            int s = (int)(pr & 0x1FFFFu);
            int pos = atomicAdd(&cur[doff], 1);
            srcs[pos] = s << 6;  // pre-shifted row offset for the gat gather
        }
    } else {
        gemm_body<128>((gemmBase + blockIdx.x - nW) * 64, X, Wl, Wr, xl, xr, N, sm);
    }
}

// standalone gemm (layer 2, K=64)
template <int K>
__global__ __launch_bounds__(256) void gemm_lr(const float* __restrict__ X,
                                               const float* __restrict__ Wl,
                                               const float* __restrict__ Wr,
                                               float* __restrict__ xl,
                                               float* __restrict__ xr, int N) {
    __shared__ float sm[GEMM_LDS_FLOATS];
    gemm_body<K>(blockIdx.x * 64, X, Wl, Wr, xl, xr, N, sm);
}

// GAT v5: one wave per dst node; 4 edge slots (g=lane>>4) x 16 lanes (t=lane&15)
// x float4 channels (c=4t..4t+3). Unnormalized softmax (logits bounded in f32).
// srcs holds pre-shifted row offsets (src*64).
__global__ __launch_bounds__(256) void gat_kernel(const float* __restrict__ xl,
                                                  const float* __restrict__ xr,
                                                  const int* __restrict__ offs,
                                                  const int* __restrict__ srcs,
                                                  const float* __restrict__ att,
                                                  const float* __restrict__ bias,
                                                  float* __restrict__ out, int N) {
    const int lane = threadIdx.x & 63;
    const int wid = threadIdx.x >> 6;
    const int n = blockIdx.x * 4 + wid;
    if (n >= N) return;
    const int g = lane >> 4;
    const int t = lane & 15;

    const float4 av = *reinterpret_cast<const float4*>(att + 4 * t);
    const float c1 = 0.6f * LOG2E, c2 = 0.4f * LOG2E;
    const float a1x = c1 * av.x, a1y = c1 * av.y, a1z = c1 * av.z, a1w = c1 * av.w;
    const float a2x = c2 * av.x, a2y = c2 * av.y, a2z = c2 * av.z, a2w = c2 * av.w;

    const float4 xr4 = *reinterpret_cast<const float4*>(xr + (size_t)n * 64 + 4 * t);
    const float4 xl4 = *reinterpret_cast<const float4*>(xl + (size_t)n * 64 + 4 * t);

    float sacc = 0.f;
    float ox = 0.f, oy = 0.f, oz = 0.f, ow = 0.f;

    // self-loop (accumulated by group 0 only)
    {
        float ux = xl4.x + xr4.x, uy = xl4.y + xr4.y;
        float uz = xl4.z + xr4.z, uw = xl4.w + xr4.w;
        float l = fmaf(a1x, ux, a2x * fabsf(ux)) + fmaf(a1y, uy, a2y * fabsf(uy))
                + fmaf(a1z, uz, a2z * fabsf(uz)) + fmaf(a1w, uw, a2w * fabsf(uw));
        float p = exp2f(quad_sum4(l));
        if (g == 0) {
            sacc = p;
            ox = xl4.x * p; oy = xl4.y * p; oz = xl4.z * p; ow = xl4.w * p;
        }
    }

    const int e0 = offs[n], e1 = offs[n + 1];
    int j = e0;
    for (; j + 4 <= e1; j += 4) {
        int off = srcs[j + g];  // uniform within group
        const float4 xv = *reinterpret_cast<const float4*>(xl + off + 4 * t);
        float ux = xv.x + xr4.x, uy = xv.y + xr4.y;
        float uz = xv.z + xr4.z, uw = xv.w + xr4.w;
        float l = fmaf(a1x, ux, a2x * fabsf(ux)) + fmaf(a1y, uy, a2y * fabsf(uy))
                + fmaf(a1z, uz, a2z * fabsf(uz)) + fmaf(a1w, uw, a2w * fabsf(uw));
        float p = exp2f(quad_sum4(l));
        sacc += p;
        ox = fmaf(xv.x, p, ox); oy = fmaf(xv.y, p, oy);
        oz = fmaf(xv.z, p, oz); ow = fmaf(xv.w, p, ow);
    }
    const int rem = e1 - j;
    if (rem > 0) {
        int off = srcs[j + min(g, rem - 1)];
        const float4 xv = *reinterpret_cast<const float4*>(xl + off + 4 * t);
        float ux = xv.x + xr4.x, uy = xv.y + xr4.y;
        float uz = xv.z + xr4.z, uw = xv.w + xr4.w;
        float l = fmaf(a1x, ux, a2x * fabsf(ux)) + fmaf(a1y, uy, a2y * fabsf(uy))
                + fmaf(a1z, uz, a2z * fabsf(uz)) + fmaf(a1w, uw, a2w * fabsf(uw));
        float p = exp2f(quad_sum4(l));
        if (g >= rem) p = 0.f;
        sacc += p;
        ox = fmaf(xv.x, p, ox); oy = fmaf(xv.y, p, oy);
        oz = fmaf(xv.z, p, oz); ow = fmaf(xv.w, p, ow);
    }

    // combine the 4 edge slots (lane ^16, ^32 flips g)
    sacc += __shfl_xor(sacc, 16, 64); sacc += __shfl_xor(sacc, 32, 64);
    ox += __shfl_xor(ox, 16, 64); ox += __shfl_xor(ox, 32, 64);
    oy += __shfl_xor(oy, 16, 64); oy += __shfl_xor(oy, 32, 64);
    oz += __shfl_xor(oz, 16, 64); oz += __shfl_xor(oz, 32, 64);
    ow += __shfl_xor(ow, 16, 64); ow += __shfl_xor(ow, 32, 64);

    if (g == 0) {
        const float4 b4 = *reinterpret_cast<const float4*>(bias + 4 * t);
        float inv = 1.f / sacc;
        float4 r = make_float4(fmaxf(fmaf(ox, inv, b4.x), 0.f),
                               fmaxf(fmaf(oy, inv, b4.y), 0.f),
                               fmaxf(fmaf(oz, inv, b4.z), 0.f),
                               fmaxf(fmaf(ow, inv, b4.w), 0.f));
        *reinterpret_cast<float4*>(out + (size_t)n * 64 + 4 * t) = r;
    }
}

extern "C" void kernel_launch(void* const* d_in, const int* in_sizes, int n_in,
                              void* d_out, int out_size, void* d_ws, size_t ws_size,
                              hipStream_t stream) {
    const float* x    = (const float*)d_in[0];
    const int*   edge = (const int*)d_in[1];
    const float* W1l  = (const float*)d_in[2];
    const float* W1r  = (const float*)d_in[3];
    const float* att1 = (const float*)d_in[4];
    const float* b1   = (const float*)d_in[5];
    const float* W2l  = (const float*)d_in[6];
    const float* W2r  = (const float*)d_in[7];
    const float* att2 = (const float*)d_in[8];
    const float* b2   = (const float*)d_in[9];

    const int N = in_sizes[0] / 128;  // 100000
    const int E = in_sizes[1] / 2;    // 1600000
    const int* esrc = edge;
    const int* edst = edge + E;

    char* ws = (char*)d_ws;
    size_t off = 0;
    auto alloc = [&](size_t bytes) {
        void* p = ws + off;
        off += (bytes + 255) & ~(size_t)255;
        return p;
    };
    float* xl     = (float*)alloc((size_t)N * 64 * 4);
    float* xr     = (float*)alloc((size_t)N * 64 * 4);
    float* h      = (float*)alloc((size_t)N * 64 * 4);
    int* deg      = (int*)alloc((size_t)N * 4);
    int* incl     = (int*)alloc((size_t)N * 4);
    int* offs     = (int*)alloc((size_t)(N + 1) * 4);
    int* partials = (int*)alloc(1024 * 4);
    int* srcs     = (int*)alloc((size_t)E * 4);
    unsigned* pairs = (unsigned*)alloc((size_t)E * 4);
    int* gh       = (int*)alloc((size_t)256 * NBLK_S * 4);
    (void)ws_size;

    hipMemsetAsync(deg, 0, (size_t)N * 4, stream);

    const int nblk = (N + 1023) >> 10;
    const int nW = (N + 511) >> 9;           // 196 windows
    const int gblk = (N + 63) / 64;          // 1563 gemm blocks
    const int GA = gblk / 2;
    const int GB = gblk - GA;

    hist_fused<<<NBLK_S, 256, 0, stream>>>(edst, deg, gh, E, nW);
    scan_a<<<nblk, 1024, 0, stream>>>(deg, incl, partials, N);
    scan_b<<<1, 1024, 0, stream>>>(partials, nblk);
    scan_c<<<(N + 255) / 256, 256, 0, stream>>>(deg, incl, partials, offs, N, E);
    sort_scan<<<nW, NBLK_S, 0, stream>>>(offs, gh, N);
    place_gemm<<<NBLK_S + GA, 256, 0, stream>>>(esrc, edst, gh, pairs, E, nW,
                                                x, W1l, W1r, xl, xr, N);
    scatter_gemm<<<nW + GB, 256, 0, stream>>>(pairs, offs, srcs, nW, GA,
                                              x, W1l, W1r, xl, xr, N);
    gat_kernel<<<(N + 3) / 4, 256, 0, stream>>>(xl, xr, offs, srcs, att1, b1, h, N);
    gemm_lr<64><<<gblk, 256, 0, stream>>>(h, W2l, W2r, xl, xr, N);
    gat_kernel<<<(N + 3) / 4, 256, 0, stream>>>(xl, xr, offs, srcs, att2, b2, (float*)d_out, N);
}